// Round 3
// baseline (696.447 us; speedup 1.0000x reference)
//
#include <hip/hip_runtime.h>
#include <stdint.h>

typedef unsigned int u32;
typedef unsigned long long u64;

#define NCELLS  3872
#define NCLS    80
#define NFLAT   309760
#define NPRE    500
#define NPAD    512
#define HH      200
#define WW      304
#define NPIX    60800
#define NWORDS  950      // 60800 / 64 exactly
#define MSTRIDE 960
#define MAXOUT  100
#define OH      427
#define OW      640
#define MH      800
#define MW      1216
#define MAXG    4096
#define MAXPAIRS 16384
#define OUT_LBL 27328000
#define OUT_SCR 27328100
#define ROWS_PER_BLK 2
#define NRBLK 214        // ceil(427/2)

#define S_THR 0.1f
#define M_THR 0.005f
#define U_THR 0.001f

// ---------------- workspace layout (bytes) ----------------
#define OFF_HIST1   0u        // 65536 u32
#define OFF_HIST2   262144u   // 256 u32 (unused now, kept zeroed)
#define OFF_META    263168u   // 16 u32: [0]cut1 [1]cntAbove1 [2]cutKey [3]gatherCnt [4]pairCnt
#define ZERO_BYTES  263232u
#define OFF_CAND    263424u   // 4096 u64
#define OFF_RAW     296192u   // 512 f32
#define OFF_LOC     298240u
#define OFF_LABEL   300288u
#define OFF_XIND    302336u
#define OFF_YIND    304384u
#define OFF_STRIDE  306432u
#define OFF_SMF     308480u
#define OFF_SCORE   310528u
#define OFF_LABELK  312576u
#define OFF_ORDER   314624u
#define OFF_SSCORE  316672u
#define OFF_TOPC    318720u   // 128 i32
#define OFF_PAIRI   319232u   // 16384 u32
#define OFF_PAIRIOU 384768u   // 16384 f32
#define OFF_W1YT0   450304u   // 800 i32
#define OFF_W1YA    453504u   // 800 f32
#define OFF_W1YB    456704u
#define OFF_W1XT0   459904u   // 1216 i32
#define OFF_W1XA    464768u
#define OFF_W1XB    469632u
#define OFF_W2YS    474496u   // 427 i32
#define OFF_W2YW    476224u   // 427*4 f32
#define OFF_W2XS    483072u   // 640 i32
#define OFF_W2XW    485632u   // 640*4 f32
#define OFF_MASKS   495872u   // 500*960 u64  (8-aligned)

#define P_U32(off) ((u32*)(ws + (off)))
#define P_I32(off) ((int*)(ws + (off)))
#define P_F32(off) ((float*)(ws + (off)))
#define P_U64(off) ((u64*)(ws + (off)))

__device__ __forceinline__ void levelMeta(int loc, int& td, int& sd, int& ng, float& st) {
  if (loc < 1600)      { td = 0;    sd = 0;   ng = 40; st = 4.f;  }
  else if (loc < 2896) { td = 1600; sd = 40;  ng = 36; st = 8.f;  }
  else if (loc < 3472) { td = 2896; sd = 76;  ng = 24; st = 16.f; }
  else if (loc < 3728) { td = 3472; sd = 100; ng = 16; st = 32.f; }
  else                 { td = 3728; sd = 116; ng = 12; st = 64.f; }
}

// -------- stage 1: top-500 selection (16-bit radix histogram + exact sort) --------
__global__ void kh1(const float* __restrict__ cate, char* __restrict__ ws) {
  int i = blockIdx.x * 256 + threadIdx.x;
  if (i >= NFLAT) return;
  float v = cate[i];
  if (v > S_THR) atomicAdd(&P_U32(OFF_HIST1)[__float_as_uint(v) >> 16], 1u);
}

// find the 16-bit bucket containing the 500th value; gather threshold = bucket<<16
__global__ __launch_bounds__(1024) void kc1(char* __restrict__ ws) {
  __shared__ u32 cs[1024];
  int t = threadIdx.x;
  const u32* h = P_U32(OFF_HIST1);
  u32 s = 0;
  for (int b = 0; b < 64; b++) s += h[t * 64 + b];
  cs[t] = s;
  __syncthreads();
  if (t == 0) {
    u32* meta = P_U32(OFF_META);
    u32 cum = 0; int cb = -1;
    for (int c = 1023; c >= 0; c--) {
      if (cum + cs[c] >= NPRE) { cb = c; break; }
      cum += cs[c];
    }
    u32 bin = 0;
    if (cb >= 0) {
      bin = (u32)(cb * 64);
      for (int b = cb * 64 + 63; b >= cb * 64; b--) {
        u32 hb = h[b];
        if (cum + hb >= NPRE) { bin = (u32)b; break; }
        cum += hb;
      }
    }
    meta[0] = bin; meta[1] = cum;
    meta[2] = bin << 16;            // gather whole cut bucket (<= ~2k cands, < MAXG)
  }
}

__global__ void kg(const float* __restrict__ cate, char* __restrict__ ws) {
  u32 key = P_U32(OFF_META)[2];
  int i = blockIdx.x * 256 + threadIdx.x;
  if (i >= NFLAT) return;
  float v = cate[i];
  if (v > S_THR) {
    u32 b = __float_as_uint(v);
    if (b >= key) {
      u32 pos = atomicAdd(&P_U32(OFF_META)[3], 1u);
      if (pos < MAXG) P_U64(OFF_CAND)[pos] = (((u64)b) << 32) | (u32)(~(u32)i);
    }
  }
}

// bitonic top-500 + candidate metadata + (fused) resize weight tables
__global__ __launch_bounds__(1024) void kselw(char* __restrict__ ws) {
  __shared__ u64 sk[MAXG];
  int tid = threadIdx.x;
  int G = (int)P_U32(OFF_META)[3]; if (G > MAXG) G = MAXG;
  const u64* cand = P_U64(OFF_CAND);
  for (int i = tid; i < MAXG; i += 1024) sk[i] = (i < G) ? cand[i] : 0ull;
  __syncthreads();
  for (int k = 2; k <= MAXG; k <<= 1) {
    for (int j = k >> 1; j > 0; j >>= 1) {
      for (int i = tid; i < MAXG; i += 1024) {
        int l = i ^ j;
        if (l > i) {
          u64 a = sk[i], b = sk[l];
          bool sw = ((i & k) == 0) ? (a < b) : (a > b);
          if (sw) { sk[i] = b; sk[l] = a; }
        }
      }
      __syncthreads();
    }
  }
  if (tid < NPAD) {
    float rawv = -1.f; int loc = 0, lab = -1, xi = 0, yi = 0; float st = 3.0e38f;
    if (tid < NPRE && tid < G) {
      u64 key = sk[tid];
      u32 b = (u32)(key >> 32);
      u32 idx = ~((u32)(key & 0xffffffffu));
      rawv = __uint_as_float(b);
      loc = (int)(idx / (u32)NCLS);
      lab = (int)(idx - (u32)loc * NCLS);
      int td, sd, ng; levelMeta(loc, td, sd, ng, st);
      int rel = loc - td;
      int row = rel / ng;
      yi = row + sd;
      xi = (rel - row * ng) + sd;
    }
    P_F32(OFF_RAW)[tid] = rawv;
    P_I32(OFF_LOC)[tid] = loc;
    P_I32(OFF_LABEL)[tid] = lab;
    P_I32(OFF_XIND)[tid] = xi;
    P_I32(OFF_YIND)[tid] = yi;
    P_F32(OFF_STRIDE)[tid] = st;
    P_F32(OFF_SCORE)[tid] = 0.f;
    P_I32(OFF_LABELK)[tid] = -1;
    P_F32(OFF_SMF)[tid] = 0.f;
  }
  // ---- fused: resize weight tables (mimic jax.image.resize f32 math) ----
  int t = tid;
  for (int r = t; r < MH; r += 1024) {
    float s1 = ((float)r + 0.5f) * 0.25f - 0.5f;
    int t0 = (int)floorf(s1);
    float f = s1 - (float)t0;
    float wa = 1.f - f, wb = f;
    bool ia = (t0 >= 0) && (t0 < HH);
    bool ib = ((t0 + 1) >= 0) && ((t0 + 1) < HH);
    float tw = (ia ? wa : 0.f) + (ib ? wb : 0.f);
    float na = ia ? (wa / tw) : 0.f;
    float nb = ib ? (wb / tw) : 0.f;
    int base; float A, B;
    if (t0 < 0) { base = 0; A = nb; B = 0.f; }
    else if (t0 >= HH - 1) { base = HH - 2; A = 0.f; B = na; }
    else { base = t0; A = na; B = nb; }
    P_I32(OFF_W1YT0)[r] = base;
    P_F32(OFF_W1YA)[r] = A;
    P_F32(OFF_W1YB)[r] = B;
  }
  for (int c = t; c < MW; c += 1024) {
    float s1 = ((float)c + 0.5f) * 0.25f - 0.5f;
    int t0 = (int)floorf(s1);
    float f = s1 - (float)t0;
    float wa = 1.f - f, wb = f;
    bool ia = (t0 >= 0) && (t0 < WW);
    bool ib = ((t0 + 1) >= 0) && ((t0 + 1) < WW);
    float tw = (ia ? wa : 0.f) + (ib ? wb : 0.f);
    float na = ia ? (wa / tw) : 0.f;
    float nb = ib ? (wb / tw) : 0.f;
    int base; float A, B;
    if (t0 < 0) { base = 0; A = nb; B = 0.f; }
    else if (t0 >= WW - 1) { base = WW - 2; A = 0.f; B = na; }
    else { base = t0; A = na; B = nb; }
    P_I32(OFF_W1XT0)[c] = base;
    P_F32(OFF_W1XA)[c] = A;
    P_F32(OFF_W1XB)[c] = B;
  }
  for (int o = t; o < OH; o += 1024) {
    const float inv = (float)(800.0 / 427.0);
    float s2 = ((float)o + 0.5f) * inv - 0.5f;
    int rA = (int)ceilf(s2 - inv);
    int rB = (int)floorf(s2 + inv);
    if (rA < 0) rA = 0;
    if (rB > MH - 1) rB = MH - 1;
    float tot = 0.f;
    for (int r = rA; r <= rB; r++) {
      float x = fabsf(s2 - (float)r) / inv;
      float w = 1.f - x; if (w < 0.f) w = 0.f;
      tot += w;
    }
    int base = rA; if (base > MH - 4) base = MH - 4;
    float o4[4] = {0.f, 0.f, 0.f, 0.f};
    for (int r = rA; r <= rB; r++) {
      float x = fabsf(s2 - (float)r) / inv;
      float w = 1.f - x; if (w < 0.f) w = 0.f;
      o4[r - base] += w / tot;
    }
    P_I32(OFF_W2YS)[o] = base;
    float* wp = P_F32(OFF_W2YW) + o * 4;
    wp[0] = o4[0]; wp[1] = o4[1]; wp[2] = o4[2]; wp[3] = o4[3];
  }
  for (int o = t; o < OW; o += 1024) {
    const float inv = (float)(1216.0 / 640.0);
    float s2 = ((float)o + 0.5f) * inv - 0.5f;
    int rA = (int)ceilf(s2 - inv);
    int rB = (int)floorf(s2 + inv);
    if (rA < 0) rA = 0;
    if (rB > MW - 1) rB = MW - 1;
    float tot = 0.f;
    for (int r = rA; r <= rB; r++) {
      float x = fabsf(s2 - (float)r) / inv;
      float w = 1.f - x; if (w < 0.f) w = 0.f;
      tot += w;
    }
    int base = rA; if (base > MW - 4) base = MW - 4;
    float o4[4] = {0.f, 0.f, 0.f, 0.f};
    for (int r = rA; r <= rB; r++) {
      float x = fabsf(s2 - (float)r) / inv;
      float w = 1.f - x; if (w < 0.f) w = 0.f;
      o4[r - base] += w / tot;
    }
    P_I32(OFF_W2XS)[o] = base;
    float* wp = P_F32(OFF_W2XW) + o * 4;
    wp[0] = o4[0]; wp[1] = o4[1]; wp[2] = o4[2]; wp[3] = o4[3];
  }
}

// -------- stage 2: per-candidate bit-packed mask + seg-score --------
__global__ __launch_bounds__(256) void kmask(const float* __restrict__ segx, const float* __restrict__ segy,
                                             char* __restrict__ ws) {
  int c = blockIdx.x;
  int tid = threadIdx.x;
  int lane = tid & 63, wv = tid >> 6;
  const float* X = segx + (size_t)P_I32(OFF_XIND)[c] * NPIX;
  const float* Y = segy + (size_t)P_I32(OFF_YIND)[c] * NPIX;
  u64* mrow = P_U64(OFF_MASKS) + (size_t)c * MSTRIDE;
  int cnt = 0;
  double ssum = 0.0;
  for (int w0 = wv; w0 < NWORDS; w0 += 4) {
    int p = (w0 << 6) + lane;
    float s = X[p] * Y[p];
    bool b = s > M_THR;
    u64 bal = __ballot(b ? 1 : 0);
    if (lane == 0) mrow[w0] = bal;
    if (b) { cnt++; ssum += (double)s; }
  }
  __shared__ int ci[256];
  __shared__ double cd[256];
  ci[tid] = cnt; cd[tid] = ssum;
  __syncthreads();
  for (int s2 = 128; s2 > 0; s2 >>= 1) {
    if (tid < s2) { ci[tid] += ci[tid + s2]; cd[tid] += cd[tid + s2]; }
    __syncthreads();
  }
  if (tid == 0) {
    float sm = (float)ci[0];
    float rawv = P_F32(OFF_RAW)[c];
    bool valid = rawv > S_THR;
    bool keep = valid && (sm > P_F32(OFF_STRIDE)[c]);
    float ssf = (float)cd[0];
    float segsc = ssf / fmaxf(sm, 1e-6f);
    P_F32(OFF_SCORE)[c] = keep ? (rawv * segsc) : 0.f;
    P_F32(OFF_SMF)[c] = keep ? sm : 0.f;
    P_I32(OFF_LABELK)[c] = keep ? P_I32(OFF_LABEL)[c] : -1;
  }
}

// -------- stage 3+4: stable descending sort of 500 scores + same-class pair list --------
__global__ __launch_bounds__(512) void ksp(char* __restrict__ ws) {
  __shared__ u64 sk[NPAD];
  __shared__ short slab[NPAD];
  __shared__ u32 scan[NPAD];
  int t = threadIdx.x;
  float sc = (t < NPRE) ? P_F32(OFF_SCORE)[t] : 0.f;
  sk[t] = (((u64)__float_as_uint(sc)) << 32) | (u32)(NPAD - 1 - t);
  __syncthreads();
  for (int k = 2; k <= NPAD; k <<= 1) {
    for (int j = k >> 1; j > 0; j >>= 1) {
      int l = t ^ j;
      if (l > t) {
        u64 a = sk[t], b = sk[l];
        bool sw = ((t & k) == 0) ? (a < b) : (a > b);
        if (sw) { sk[t] = b; sk[l] = a; }
      }
      __syncthreads();
    }
  }
  int ord = NPAD - 1 - (int)(sk[t] & 0xffffffffu);
  P_I32(OFF_ORDER)[t] = ord;
  P_F32(OFF_SSCORE)[t] = __uint_as_float((u32)(sk[t] >> 32));
  // pairs
  const int* labelK = P_I32(OFF_LABELK);
  int lab = (t < NPRE) ? labelK[ord] : -1;
  slab[t] = (short)lab;
  __syncthreads();
  u32 cnt = 0;
  if (lab >= 0) {
    short lj = (short)lab;
    for (int i = 0; i < t; i++) if (slab[i] == lj) cnt++;
  }
  scan[t] = cnt;
  __syncthreads();
  for (int off = 1; off < NPAD; off <<= 1) {
    u32 v = (t >= off) ? scan[t - off] : 0u;
    __syncthreads();
    scan[t] += v;
    __syncthreads();
  }
  if (t == NPAD - 1) {
    u32 tot = scan[t];
    P_U32(OFF_META)[4] = (tot > MAXPAIRS) ? MAXPAIRS : tot;
  }
  if (lab >= 0 && cnt) {
    u32 pos = scan[t] - cnt;
    short lj = (short)lab;
    u32* pairI = P_U32(OFF_PAIRI);
    for (int i = 0; i < t; i++) {
      if (slab[i] == lj) {
        if (pos < MAXPAIRS) pairI[pos] = (((u32)i) << 16) | (u32)t;
        pos++;
      }
    }
  }
}

__global__ __launch_bounds__(64) void kpiou(char* __restrict__ ws) {
  int P = (int)P_U32(OFF_META)[4]; if (P > MAXPAIRS) P = MAXPAIRS;
  const int* order = P_I32(OFF_ORDER);
  const float* smf = P_F32(OFF_SMF);
  const u64* masks = P_U64(OFF_MASKS);
  for (int p = blockIdx.x; p < P; p += gridDim.x) {
    u32 ij = P_U32(OFF_PAIRI)[p];
    int oi = order[ij >> 16];
    int oj = order[ij & 0xffffu];
    const u64* mi = masks + (size_t)oi * MSTRIDE;
    const u64* mj = masks + (size_t)oj * MSTRIDE;
    int inter = 0;
    for (int w = threadIdx.x; w < NWORDS; w += 64)
      inter += (int)__popcll(mi[w] & mj[w]);
    for (int off = 32; off > 0; off >>= 1)
      inter += __shfl_down(inter, off);
    if (threadIdx.x == 0) {
      float fi = (float)inter;
      float uni = (smf[oj] + smf[oi]) - fi;
      float iou = (uni > 0.f) ? (fi / fmaxf(uni, 1e-12f)) : 0.f;
      P_F32(OFF_PAIRIOU)[p] = iou;
    }
  }
}

// -------- stage 5: matrix-NMS decay + top-100 + labels/scores out --------
__global__ __launch_bounds__(512) void knms(char* __restrict__ ws, float* __restrict__ out) {
  __shared__ int compI[NPAD];
  __shared__ int coefI[NPAD];
  __shared__ u64 sk[NPAD];
  int t = threadIdx.x;
  int P = (int)P_U32(OFF_META)[4]; if (P > MAXPAIRS) P = MAXPAIRS;
  const u32* pairI = P_U32(OFF_PAIRI);
  const float* pairIou = P_F32(OFF_PAIRIOU);
  const float* sscore = P_F32(OFF_SSCORE);
  const int* order = P_I32(OFF_ORDER);
  const int* labelK = P_I32(OFF_LABELK);
  int* topc = P_I32(OFF_TOPC);
  compI[t] = 0;
  coefI[t] = __float_as_int(1.0f);
  __syncthreads();
  for (int p = t; p < P; p += 512) {
    int j = (int)(pairI[p] & 0xffffu);
    atomicMax(&compI[j], __float_as_int(pairIou[p]));
  }
  __syncthreads();
  for (int p = t; p < P; p += 512) {
    u32 ij = pairI[p];
    int i = (int)(ij >> 16), j = (int)(ij & 0xffffu);
    float x = pairIou[p];
    float c = __int_as_float(compI[i]);
    float x2 = x * x, c2 = c * c;
    float r = (float)exp(-2.0 * ((double)x2 - (double)c2));
    atomicMin(&coefI[j], __float_as_int(r));
  }
  __syncthreads();
  float ns = 0.f;
  if (t < NPRE) {
    ns = sscore[t] * __int_as_float(coefI[t]);
    ns = (ns > U_THR) ? ns : 0.f;
  }
  sk[t] = (((u64)__float_as_uint(ns)) << 32) | (u32)(NPAD - 1 - t);
  __syncthreads();
  for (int k = 2; k <= NPAD; k <<= 1) {
    for (int j = k >> 1; j > 0; j >>= 1) {
      int l = t ^ j;
      if (l > t) {
        u64 a = sk[t], b = sk[l];
        bool sw = ((t & k) == 0) ? (a < b) : (a > b);
        if (sw) { sk[t] = b; sk[l] = a; }
      }
      __syncthreads();
    }
  }
  if (t < MAXOUT) {
    u64 key = sk[t];
    int pos = NPAD - 1 - (int)(key & 0xffffffffu);
    int cand = order[pos];
    topc[t] = cand;
    out[OUT_LBL + t] = (float)labelK[cand];
    out[OUT_SCR + t] = __uint_as_float((u32)(key >> 32));
  }
}

// -------- stage 7: fused double-resize + binarize; one block = (mask, 2 out-rows) --------
// Shares src-row products, t1 mid-rows and x-upsampled mid-rows across the 2 rows;
// y-contraction (yrow) computed once per mid-column. Bit-identical fma chains to v2.
__global__ __launch_bounds__(256) void kout(const float* __restrict__ segx, const float* __restrict__ segy,
                                            char* __restrict__ ws, float* __restrict__ out) {
  __shared__ float ss[4][WW];    // src-row products X*Y
  __shared__ float t1s[6][WW];   // y-interp mid rows (stage-1 vertical)
  __shared__ float ups[6][MW];   // full mid-resolution rows (f32-rounded)
  __shared__ float yrs[2][MW];   // per-out-row y-contracted mid columns
  int bx = blockIdx.x;
  int kk = bx / NRBLK;
  int r2 = bx - kk * NRBLK;
  int oy0 = r2 * ROWS_PER_BLK;
  int nrow = (oy0 + 1 < OH) ? 2 : 1;
  int tid = threadIdx.x;
  int cand = P_I32(OFF_TOPC)[kk];
  const float* X = segx + (size_t)P_I32(OFF_XIND)[cand] * NPIX;
  const float* Y = segy + (size_t)P_I32(OFF_YIND)[cand] * NPIX;
  const int* w2ys = P_I32(OFF_W2YS);
  int rb = w2ys[oy0];
  const int* w1yT0 = P_I32(OFF_W1YT0);
  int smin = w1yT0[rb];
  // stage 0: src-row products (<=4 distinct source rows feed the <=6 mid rows)
  for (int idx = tid; idx < 4 * WW; idx += 256) {
    int q = idx / WW;
    int u = idx - q * WW;
    int row = smin + q; if (row > HH - 1) row = HH - 1;
    ss[q][u] = X[row * WW + u] * Y[row * WW + u];
  }
  __syncthreads();
  // stage 1: t1 for the <=6 mid rows
  const float* w1yA = P_F32(OFF_W1YA);
  const float* w1yB = P_F32(OFF_W1YB);
  for (int idx = tid; idx < 6 * WW; idx += 256) {
    int mr = idx / WW;
    int u = idx - mr * WW;
    int r = rb + mr; if (r > MH - 1) r = MH - 1;
    int i0 = w1yT0[r] - smin;          // in [0,2]
    t1s[mr][u] = fmaf(w1yB[r], ss[i0 + 1][u], w1yA[r] * ss[i0][u]);
  }
  __syncthreads();
  // stage 2: x-upsample to mid resolution
  const int* w1xT0 = P_I32(OFF_W1XT0);
  const float* w1xA = P_F32(OFF_W1XA);
  const float* w1xB = P_F32(OFF_W1XB);
  for (int idx = tid; idx < 6 * MW; idx += 256) {
    int mr = idx / MW;
    int cc = idx - mr * MW;
    int u0 = w1xT0[cc];
    ups[mr][cc] = fmaf(w1xB[cc], t1s[mr][u0 + 1], w1xA[cc] * t1s[mr][u0]);
  }
  __syncthreads();
  // stage 3a: y-contraction once per mid column per out row
  const float* w2yw = P_F32(OFF_W2YW);
  for (int idx = tid; idx < nrow * MW; idx += 256) {
    int rr = idx / MW;
    int cc = idx - rr * MW;
    int oy = oy0 + rr;
    int off = w2ys[oy] - rb;           // in [0,2]
    const float* wy = w2yw + oy * 4;
    float v = wy[0] * ups[off][cc];
    v = fmaf(wy[1], ups[off + 1][cc], v);
    v = fmaf(wy[2], ups[off + 2][cc], v);
    v = fmaf(wy[3], ups[off + 3][cc], v);
    yrs[rr][cc] = v;
  }
  __syncthreads();
  // stage 3b: x-contraction + binarize + store
  const int* w2xS = P_I32(OFF_W2XS);
  const float* w2xW = P_F32(OFF_W2XW);
  for (int idx = tid; idx < nrow * OW; idx += 256) {
    int rr = idx / OW;
    int ox = idx - rr * OW;
    int oy = oy0 + rr;
    int cb = w2xS[ox];
    const float* wx = w2xW + ox * 4;
    float acc = wx[0] * yrs[rr][cb];
    acc = fmaf(wx[1], yrs[rr][cb + 1], acc);
    acc = fmaf(wx[2], yrs[rr][cb + 2], acc);
    acc = fmaf(wx[3], yrs[rr][cb + 3], acc);
    out[((size_t)kk * OH + oy) * OW + ox] = (acc > M_THR) ? 1.0f : 0.0f;
  }
}

extern "C" void kernel_launch(void* const* d_in, const int* in_sizes, int n_in,
                              void* d_out, int out_size, void* d_ws, size_t ws_size,
                              hipStream_t stream) {
  (void)in_sizes; (void)n_in; (void)out_size; (void)ws_size;
  const float* cate = (const float*)d_in[0];
  const float* segx = (const float*)d_in[1];
  const float* segy = (const float*)d_in[2];
  char* ws = (char*)d_ws;
  float* out = (float*)d_out;

  hipMemsetAsync(ws, 0, ZERO_BYTES, stream);

  dim3 gFlat((NFLAT + 255) / 256);
  hipLaunchKernelGGL(kh1, gFlat, dim3(256), 0, stream, cate, ws);
  hipLaunchKernelGGL(kc1, dim3(1), dim3(1024), 0, stream, ws);
  hipLaunchKernelGGL(kg, gFlat, dim3(256), 0, stream, cate, ws);
  hipLaunchKernelGGL(kselw, dim3(1), dim3(1024), 0, stream, ws);
  hipLaunchKernelGGL(kmask, dim3(NPRE), dim3(256), 0, stream, segx, segy, ws);
  hipLaunchKernelGGL(ksp, dim3(1), dim3(512), 0, stream, ws);
  hipLaunchKernelGGL(kpiou, dim3(2048), dim3(64), 0, stream, ws);
  hipLaunchKernelGGL(knms, dim3(1), dim3(512), 0, stream, ws, out);
  hipLaunchKernelGGL(kout, dim3(MAXOUT * NRBLK), dim3(256), 0, stream, segx, segy, ws, out);
}

// Round 4
// 553.202 us; speedup vs baseline: 1.2589x; 1.2589x over previous
//
#include <hip/hip_runtime.h>
#include <stdint.h>

typedef unsigned int u32;
typedef unsigned long long u64;

#define NCELLS  3872
#define NCLS    80
#define NFLAT   309760
#define NPRE    500
#define NPAD    512
#define HH      200
#define WW      304
#define NPIX    60800
#define NWORDS  950      // 60800 / 64 exactly
#define MSTRIDE 960
#define MAXOUT  100
#define OH      427
#define OW      640
#define MH      800
#define MW      1216
#define MAXG    4096
#define MAXPAIRS 16384
#define OUT_LBL 27328000
#define OUT_SCR 27328100
#define ROWS_PER_BLK 2
#define NRBLK 214        // ceil(427/2)

#define S_THR 0.1f
#define M_THR 0.005f
#define U_THR 0.001f

// ---------------- workspace layout (bytes) ----------------
#define OFF_HIST1   0u        // 65536 u32
#define OFF_HIST2   262144u   // 256 u32 (unused now, kept zeroed)
#define OFF_META    263168u   // 16 u32: [0]cut1 [1]cntAbove1 [2]cutKey [3]gatherCnt [4]pairCnt
#define ZERO_BYTES  263232u
#define OFF_CAND    263424u   // 4096 u64
#define OFF_RAW     296192u   // 512 f32
#define OFF_LOC     298240u
#define OFF_LABEL   300288u
#define OFF_XIND    302336u
#define OFF_YIND    304384u
#define OFF_STRIDE  306432u
#define OFF_SMF     308480u
#define OFF_SCORE   310528u
#define OFF_LABELK  312576u
#define OFF_ORDER   314624u
#define OFF_SSCORE  316672u
#define OFF_TOPC    318720u   // 128 i32
#define OFF_PAIRI   319232u   // 16384 u32
#define OFF_PAIRIOU 384768u   // 16384 f32
#define OFF_W1YT0   450304u   // 800 i32
#define OFF_W1YA    453504u   // 800 f32
#define OFF_W1YB    456704u
#define OFF_W1XT0   459904u   // 1216 i32
#define OFF_W1XA    464768u
#define OFF_W1XB    469632u
#define OFF_W2YS    474496u   // 427 i32
#define OFF_W2YW    476224u   // 427*4 f32
#define OFF_W2XS    483072u   // 640 i32
#define OFF_W2XW    485632u   // 640*4 f32
#define OFF_MASKS   495872u   // 500*960 u64  (8-aligned)

#define P_U32(off) ((u32*)(ws + (off)))
#define P_I32(off) ((int*)(ws + (off)))
#define P_F32(off) ((float*)(ws + (off)))
#define P_U64(off) ((u64*)(ws + (off)))

__device__ __forceinline__ void levelMeta(int loc, int& td, int& sd, int& ng, float& st) {
  if (loc < 1600)      { td = 0;    sd = 0;   ng = 40; st = 4.f;  }
  else if (loc < 2896) { td = 1600; sd = 40;  ng = 36; st = 8.f;  }
  else if (loc < 3472) { td = 2896; sd = 76;  ng = 24; st = 16.f; }
  else if (loc < 3728) { td = 3472; sd = 100; ng = 16; st = 32.f; }
  else                 { td = 3728; sd = 116; ng = 12; st = 64.f; }
}

// -------- stage 1: top-500 selection (16-bit radix histogram + exact sort) --------
__global__ void kh1(const float* __restrict__ cate, char* __restrict__ ws) {
  int i = blockIdx.x * 256 + threadIdx.x;
  if (i >= NFLAT) return;
  float v = cate[i];
  if (v > S_THR) atomicAdd(&P_U32(OFF_HIST1)[__float_as_uint(v) >> 16], 1u);
}

// find the 16-bit bucket containing the 500th value; gather threshold = bucket<<16
__global__ __launch_bounds__(1024) void kc1(char* __restrict__ ws) {
  __shared__ u32 cs[1024];
  int t = threadIdx.x;
  const u32* h = P_U32(OFF_HIST1);
  u32 s = 0;
  for (int b = 0; b < 64; b++) s += h[t * 64 + b];
  cs[t] = s;
  __syncthreads();
  if (t == 0) {
    u32* meta = P_U32(OFF_META);
    u32 cum = 0; int cb = -1;
    for (int c = 1023; c >= 0; c--) {
      if (cum + cs[c] >= NPRE) { cb = c; break; }
      cum += cs[c];
    }
    u32 bin = 0;
    if (cb >= 0) {
      bin = (u32)(cb * 64);
      for (int b = cb * 64 + 63; b >= cb * 64; b--) {
        u32 hb = h[b];
        if (cum + hb >= NPRE) { bin = (u32)b; break; }
        cum += hb;
      }
    }
    meta[0] = bin; meta[1] = cum;
    meta[2] = bin << 16;            // gather whole cut bucket (<= ~2k cands, < MAXG)
  }
}

__global__ void kg(const float* __restrict__ cate, char* __restrict__ ws) {
  u32 key = P_U32(OFF_META)[2];
  int i = blockIdx.x * 256 + threadIdx.x;
  if (i >= NFLAT) return;
  float v = cate[i];
  if (v > S_THR) {
    u32 b = __float_as_uint(v);
    if (b >= key) {
      u32 pos = atomicAdd(&P_U32(OFF_META)[3], 1u);
      if (pos < MAXG) P_U64(OFF_CAND)[pos] = (((u64)b) << 32) | (u32)(~(u32)i);
    }
  }
}

// bitonic top-500 + candidate metadata + (fused) resize weight tables
__global__ __launch_bounds__(1024) void kselw(char* __restrict__ ws) {
  __shared__ u64 sk[MAXG];
  int tid = threadIdx.x;
  int G = (int)P_U32(OFF_META)[3]; if (G > MAXG) G = MAXG;
  const u64* cand = P_U64(OFF_CAND);
  for (int i = tid; i < MAXG; i += 1024) sk[i] = (i < G) ? cand[i] : 0ull;
  __syncthreads();
  for (int k = 2; k <= MAXG; k <<= 1) {
    for (int j = k >> 1; j > 0; j >>= 1) {
      for (int i = tid; i < MAXG; i += 1024) {
        int l = i ^ j;
        if (l > i) {
          u64 a = sk[i], b = sk[l];
          bool sw = ((i & k) == 0) ? (a < b) : (a > b);
          if (sw) { sk[i] = b; sk[l] = a; }
        }
      }
      __syncthreads();
    }
  }
  if (tid < NPAD) {
    float rawv = -1.f; int loc = 0, lab = -1, xi = 0, yi = 0; float st = 3.0e38f;
    if (tid < NPRE && tid < G) {
      u64 key = sk[tid];
      u32 b = (u32)(key >> 32);
      u32 idx = ~((u32)(key & 0xffffffffu));
      rawv = __uint_as_float(b);
      loc = (int)(idx / (u32)NCLS);
      lab = (int)(idx - (u32)loc * NCLS);
      int td, sd, ng; levelMeta(loc, td, sd, ng, st);
      int rel = loc - td;
      int row = rel / ng;
      yi = row + sd;
      xi = (rel - row * ng) + sd;
    }
    P_F32(OFF_RAW)[tid] = rawv;
    P_I32(OFF_LOC)[tid] = loc;
    P_I32(OFF_LABEL)[tid] = lab;
    P_I32(OFF_XIND)[tid] = xi;
    P_I32(OFF_YIND)[tid] = yi;
    P_F32(OFF_STRIDE)[tid] = st;
    P_F32(OFF_SCORE)[tid] = 0.f;
    P_I32(OFF_LABELK)[tid] = -1;
    P_F32(OFF_SMF)[tid] = 0.f;
  }
  // ---- fused: resize weight tables (mimic jax.image.resize f32 math) ----
  int t = tid;
  for (int r = t; r < MH; r += 1024) {
    float s1 = ((float)r + 0.5f) * 0.25f - 0.5f;
    int t0 = (int)floorf(s1);
    float f = s1 - (float)t0;
    float wa = 1.f - f, wb = f;
    bool ia = (t0 >= 0) && (t0 < HH);
    bool ib = ((t0 + 1) >= 0) && ((t0 + 1) < HH);
    float tw = (ia ? wa : 0.f) + (ib ? wb : 0.f);
    float na = ia ? (wa / tw) : 0.f;
    float nb = ib ? (wb / tw) : 0.f;
    int base; float A, B;
    if (t0 < 0) { base = 0; A = nb; B = 0.f; }
    else if (t0 >= HH - 1) { base = HH - 2; A = 0.f; B = na; }
    else { base = t0; A = na; B = nb; }
    P_I32(OFF_W1YT0)[r] = base;
    P_F32(OFF_W1YA)[r] = A;
    P_F32(OFF_W1YB)[r] = B;
  }
  for (int c = t; c < MW; c += 1024) {
    float s1 = ((float)c + 0.5f) * 0.25f - 0.5f;
    int t0 = (int)floorf(s1);
    float f = s1 - (float)t0;
    float wa = 1.f - f, wb = f;
    bool ia = (t0 >= 0) && (t0 < WW);
    bool ib = ((t0 + 1) >= 0) && ((t0 + 1) < WW);
    float tw = (ia ? wa : 0.f) + (ib ? wb : 0.f);
    float na = ia ? (wa / tw) : 0.f;
    float nb = ib ? (wb / tw) : 0.f;
    int base; float A, B;
    if (t0 < 0) { base = 0; A = nb; B = 0.f; }
    else if (t0 >= WW - 1) { base = WW - 2; A = 0.f; B = na; }
    else { base = t0; A = na; B = nb; }
    P_I32(OFF_W1XT0)[c] = base;
    P_F32(OFF_W1XA)[c] = A;
    P_F32(OFF_W1XB)[c] = B;
  }
  for (int o = t; o < OH; o += 1024) {
    const float inv = (float)(800.0 / 427.0);
    float s2 = ((float)o + 0.5f) * inv - 0.5f;
    int rA = (int)ceilf(s2 - inv);
    int rB = (int)floorf(s2 + inv);
    if (rA < 0) rA = 0;
    if (rB > MH - 1) rB = MH - 1;
    float tot = 0.f;
    for (int r = rA; r <= rB; r++) {
      float x = fabsf(s2 - (float)r) / inv;
      float w = 1.f - x; if (w < 0.f) w = 0.f;
      tot += w;
    }
    int base = rA; if (base > MH - 4) base = MH - 4;
    float o4[4] = {0.f, 0.f, 0.f, 0.f};
    for (int r = rA; r <= rB; r++) {
      float x = fabsf(s2 - (float)r) / inv;
      float w = 1.f - x; if (w < 0.f) w = 0.f;
      o4[r - base] += w / tot;
    }
    P_I32(OFF_W2YS)[o] = base;
    float* wp = P_F32(OFF_W2YW) + o * 4;
    wp[0] = o4[0]; wp[1] = o4[1]; wp[2] = o4[2]; wp[3] = o4[3];
  }
  for (int o = t; o < OW; o += 1024) {
    const float inv = (float)(1216.0 / 640.0);
    float s2 = ((float)o + 0.5f) * inv - 0.5f;
    int rA = (int)ceilf(s2 - inv);
    int rB = (int)floorf(s2 + inv);
    if (rA < 0) rA = 0;
    if (rB > MW - 1) rB = MW - 1;
    float tot = 0.f;
    for (int r = rA; r <= rB; r++) {
      float x = fabsf(s2 - (float)r) / inv;
      float w = 1.f - x; if (w < 0.f) w = 0.f;
      tot += w;
    }
    int base = rA; if (base > MW - 4) base = MW - 4;
    float o4[4] = {0.f, 0.f, 0.f, 0.f};
    for (int r = rA; r <= rB; r++) {
      float x = fabsf(s2 - (float)r) / inv;
      float w = 1.f - x; if (w < 0.f) w = 0.f;
      o4[r - base] += w / tot;
    }
    P_I32(OFF_W2XS)[o] = base;
    float* wp = P_F32(OFF_W2XW) + o * 4;
    wp[0] = o4[0]; wp[1] = o4[1]; wp[2] = o4[2]; wp[3] = o4[3];
  }
}

// -------- stage 2: per-candidate bit-packed mask + seg-score --------
__global__ __launch_bounds__(256) void kmask(const float* __restrict__ segx, const float* __restrict__ segy,
                                             char* __restrict__ ws) {
  int c = blockIdx.x;
  int tid = threadIdx.x;
  int lane = tid & 63, wv = tid >> 6;
  const float* X = segx + (size_t)P_I32(OFF_XIND)[c] * NPIX;
  const float* Y = segy + (size_t)P_I32(OFF_YIND)[c] * NPIX;
  u64* mrow = P_U64(OFF_MASKS) + (size_t)c * MSTRIDE;
  int cnt = 0;
  double ssum = 0.0;
  for (int w0 = wv; w0 < NWORDS; w0 += 4) {
    int p = (w0 << 6) + lane;
    float s = X[p] * Y[p];
    bool b = s > M_THR;
    u64 bal = __ballot(b ? 1 : 0);
    if (lane == 0) mrow[w0] = bal;
    if (b) { cnt++; ssum += (double)s; }
  }
  __shared__ int ci[256];
  __shared__ double cd[256];
  ci[tid] = cnt; cd[tid] = ssum;
  __syncthreads();
  for (int s2 = 128; s2 > 0; s2 >>= 1) {
    if (tid < s2) { ci[tid] += ci[tid + s2]; cd[tid] += cd[tid + s2]; }
    __syncthreads();
  }
  if (tid == 0) {
    float sm = (float)ci[0];
    float rawv = P_F32(OFF_RAW)[c];
    bool valid = rawv > S_THR;
    bool keep = valid && (sm > P_F32(OFF_STRIDE)[c]);
    float ssf = (float)cd[0];
    float segsc = ssf / fmaxf(sm, 1e-6f);
    P_F32(OFF_SCORE)[c] = keep ? (rawv * segsc) : 0.f;
    P_F32(OFF_SMF)[c] = keep ? sm : 0.f;
    P_I32(OFF_LABELK)[c] = keep ? P_I32(OFF_LABEL)[c] : -1;
  }
}

// -------- stage 3+4: stable descending sort of 500 scores + same-class pair list --------
__global__ __launch_bounds__(512) void ksp(char* __restrict__ ws) {
  __shared__ u64 sk[NPAD];
  __shared__ short slab[NPAD];
  __shared__ u32 scan[NPAD];
  int t = threadIdx.x;
  float sc = (t < NPRE) ? P_F32(OFF_SCORE)[t] : 0.f;
  sk[t] = (((u64)__float_as_uint(sc)) << 32) | (u32)(NPAD - 1 - t);
  __syncthreads();
  for (int k = 2; k <= NPAD; k <<= 1) {
    for (int j = k >> 1; j > 0; j >>= 1) {
      int l = t ^ j;
      if (l > t) {
        u64 a = sk[t], b = sk[l];
        bool sw = ((t & k) == 0) ? (a < b) : (a > b);
        if (sw) { sk[t] = b; sk[l] = a; }
      }
      __syncthreads();
    }
  }
  int ord = NPAD - 1 - (int)(sk[t] & 0xffffffffu);
  P_I32(OFF_ORDER)[t] = ord;
  P_F32(OFF_SSCORE)[t] = __uint_as_float((u32)(sk[t] >> 32));
  // pairs
  const int* labelK = P_I32(OFF_LABELK);
  int lab = (t < NPRE) ? labelK[ord] : -1;
  slab[t] = (short)lab;
  __syncthreads();
  u32 cnt = 0;
  if (lab >= 0) {
    short lj = (short)lab;
    for (int i = 0; i < t; i++) if (slab[i] == lj) cnt++;
  }
  scan[t] = cnt;
  __syncthreads();
  for (int off = 1; off < NPAD; off <<= 1) {
    u32 v = (t >= off) ? scan[t - off] : 0u;
    __syncthreads();
    scan[t] += v;
    __syncthreads();
  }
  if (t == NPAD - 1) {
    u32 tot = scan[t];
    P_U32(OFF_META)[4] = (tot > MAXPAIRS) ? MAXPAIRS : tot;
  }
  if (lab >= 0 && cnt) {
    u32 pos = scan[t] - cnt;
    short lj = (short)lab;
    u32* pairI = P_U32(OFF_PAIRI);
    for (int i = 0; i < t; i++) {
      if (slab[i] == lj) {
        if (pos < MAXPAIRS) pairI[pos] = (((u32)i) << 16) | (u32)t;
        pos++;
      }
    }
  }
}

__global__ __launch_bounds__(64) void kpiou(char* __restrict__ ws) {
  int P = (int)P_U32(OFF_META)[4]; if (P > MAXPAIRS) P = MAXPAIRS;
  const int* order = P_I32(OFF_ORDER);
  const float* smf = P_F32(OFF_SMF);
  const u64* masks = P_U64(OFF_MASKS);
  for (int p = blockIdx.x; p < P; p += gridDim.x) {
    u32 ij = P_U32(OFF_PAIRI)[p];
    int oi = order[ij >> 16];
    int oj = order[ij & 0xffffu];
    const u64* mi = masks + (size_t)oi * MSTRIDE;
    const u64* mj = masks + (size_t)oj * MSTRIDE;
    int inter = 0;
    for (int w = threadIdx.x; w < NWORDS; w += 64)
      inter += (int)__popcll(mi[w] & mj[w]);
    for (int off = 32; off > 0; off >>= 1)
      inter += __shfl_down(inter, off);
    if (threadIdx.x == 0) {
      float fi = (float)inter;
      float uni = (smf[oj] + smf[oi]) - fi;
      float iou = (uni > 0.f) ? (fi / fmaxf(uni, 1e-12f)) : 0.f;
      P_F32(OFF_PAIRIOU)[p] = iou;
    }
  }
}

// -------- stage 5: matrix-NMS decay + top-100 + labels/scores out --------
__global__ __launch_bounds__(512) void knms(char* __restrict__ ws, float* __restrict__ out) {
  __shared__ int compI[NPAD];
  __shared__ int coefI[NPAD];
  __shared__ u64 sk[NPAD];
  int t = threadIdx.x;
  int P = (int)P_U32(OFF_META)[4]; if (P > MAXPAIRS) P = MAXPAIRS;
  const u32* pairI = P_U32(OFF_PAIRI);
  const float* pairIou = P_F32(OFF_PAIRIOU);
  const float* sscore = P_F32(OFF_SSCORE);
  const int* order = P_I32(OFF_ORDER);
  const int* labelK = P_I32(OFF_LABELK);
  int* topc = P_I32(OFF_TOPC);
  compI[t] = 0;
  coefI[t] = __float_as_int(1.0f);
  __syncthreads();
  for (int p = t; p < P; p += 512) {
    int j = (int)(pairI[p] & 0xffffu);
    atomicMax(&compI[j], __float_as_int(pairIou[p]));
  }
  __syncthreads();
  for (int p = t; p < P; p += 512) {
    u32 ij = pairI[p];
    int i = (int)(ij >> 16), j = (int)(ij & 0xffffu);
    float x = pairIou[p];
    float c = __int_as_float(compI[i]);
    float x2 = x * x, c2 = c * c;
    float r = (float)exp(-2.0 * ((double)x2 - (double)c2));
    atomicMin(&coefI[j], __float_as_int(r));
  }
  __syncthreads();
  float ns = 0.f;
  if (t < NPRE) {
    ns = sscore[t] * __int_as_float(coefI[t]);
    ns = (ns > U_THR) ? ns : 0.f;
  }
  sk[t] = (((u64)__float_as_uint(ns)) << 32) | (u32)(NPAD - 1 - t);
  __syncthreads();
  for (int k = 2; k <= NPAD; k <<= 1) {
    for (int j = k >> 1; j > 0; j >>= 1) {
      int l = t ^ j;
      if (l > t) {
        u64 a = sk[t], b = sk[l];
        bool sw = ((t & k) == 0) ? (a < b) : (a > b);
        if (sw) { sk[t] = b; sk[l] = a; }
      }
      __syncthreads();
    }
  }
  if (t < MAXOUT) {
    u64 key = sk[t];
    int pos = NPAD - 1 - (int)(key & 0xffffffffu);
    int cand = order[pos];
    topc[t] = cand;
    out[OUT_LBL + t] = (float)labelK[cand];
    out[OUT_SCR + t] = __uint_as_float((u32)(key >> 32));
  }
}

// -------- stage 7: fused double-resize + binarize; one block = (mask, 2 out-rows) --------
// LDS: src rows + t1 mid rows + per-out-row y-contraction; the x-upsample (ups)
// is recomputed on the fly inside the y-contraction with the identical single-fmaf
// expression -> bit-exact, 29 KB less LDS than round 3 (occupancy restored).
__global__ __launch_bounds__(256) void kout(const float* __restrict__ segx, const float* __restrict__ segy,
                                            char* __restrict__ ws, float* __restrict__ out) {
  __shared__ float ss[4][WW];    // src-row products X*Y
  __shared__ float t1s[6][WW];   // y-interp mid rows (stage-1 vertical)
  __shared__ float yrs[2][MW];   // per-out-row y-contracted mid columns
  int bx = blockIdx.x;
  int kk = bx / NRBLK;
  int r2 = bx - kk * NRBLK;
  int oy0 = r2 * ROWS_PER_BLK;
  int nrow = (oy0 + 1 < OH) ? 2 : 1;
  int tid = threadIdx.x;
  int cand = P_I32(OFF_TOPC)[kk];
  const float* X = segx + (size_t)P_I32(OFF_XIND)[cand] * NPIX;
  const float* Y = segy + (size_t)P_I32(OFF_YIND)[cand] * NPIX;
  const int* w2ys = P_I32(OFF_W2YS);
  int rb = w2ys[oy0];
  const int* w1yT0 = P_I32(OFF_W1YT0);
  int smin = w1yT0[rb];
  // stage 0: src-row products (<=4 distinct source rows feed the <=6 mid rows)
  for (int idx = tid; idx < 4 * WW; idx += 256) {
    int q = idx / WW;
    int u = idx - q * WW;
    int row = smin + q; if (row > HH - 1) row = HH - 1;
    ss[q][u] = X[row * WW + u] * Y[row * WW + u];
  }
  __syncthreads();
  // stage 1: t1 for the <=6 mid rows
  const float* w1yA = P_F32(OFF_W1YA);
  const float* w1yB = P_F32(OFF_W1YB);
  for (int idx = tid; idx < 6 * WW; idx += 256) {
    int mr = idx / WW;
    int u = idx - mr * WW;
    int r = rb + mr; if (r > MH - 1) r = MH - 1;
    int i0 = w1yT0[r] - smin;          // in [0,2]
    t1s[mr][u] = fmaf(w1yB[r], ss[i0 + 1][u], w1yA[r] * ss[i0][u]);
  }
  __syncthreads();
  // stage 2+3a fused: x-upsample taps on the fly + y-contraction, once per mid column
  const int* w1xT0 = P_I32(OFF_W1XT0);
  const float* w1xA = P_F32(OFF_W1XA);
  const float* w1xB = P_F32(OFF_W1XB);
  const float* w2yw = P_F32(OFF_W2YW);
  for (int idx = tid; idx < nrow * MW; idx += 256) {
    int rr = idx / MW;
    int cc = idx - rr * MW;
    int oy = oy0 + rr;
    int off = w2ys[oy] - rb;           // in [0,2]
    const float* wy = w2yw + oy * 4;
    int u0 = w1xT0[cc];
    float xa = w1xA[cc], xb = w1xB[cc];
    float up0 = fmaf(xb, t1s[off][u0 + 1],     xa * t1s[off][u0]);
    float up1 = fmaf(xb, t1s[off + 1][u0 + 1], xa * t1s[off + 1][u0]);
    float up2 = fmaf(xb, t1s[off + 2][u0 + 1], xa * t1s[off + 2][u0]);
    float up3 = fmaf(xb, t1s[off + 3][u0 + 1], xa * t1s[off + 3][u0]);
    float v = wy[0] * up0;
    v = fmaf(wy[1], up1, v);
    v = fmaf(wy[2], up2, v);
    v = fmaf(wy[3], up3, v);
    yrs[rr][cc] = v;
  }
  __syncthreads();
  // stage 3b: x-contraction + binarize + store
  const int* w2xS = P_I32(OFF_W2XS);
  const float* w2xW = P_F32(OFF_W2XW);
  for (int idx = tid; idx < nrow * OW; idx += 256) {
    int rr = idx / OW;
    int ox = idx - rr * OW;
    int oy = oy0 + rr;
    int cb = w2xS[ox];
    const float* wx = w2xW + ox * 4;
    float acc = wx[0] * yrs[rr][cb];
    acc = fmaf(wx[1], yrs[rr][cb + 1], acc);
    acc = fmaf(wx[2], yrs[rr][cb + 2], acc);
    acc = fmaf(wx[3], yrs[rr][cb + 3], acc);
    out[((size_t)kk * OH + oy) * OW + ox] = (acc > M_THR) ? 1.0f : 0.0f;
  }
}

extern "C" void kernel_launch(void* const* d_in, const int* in_sizes, int n_in,
                              void* d_out, int out_size, void* d_ws, size_t ws_size,
                              hipStream_t stream) {
  (void)in_sizes; (void)n_in; (void)out_size; (void)ws_size;
  const float* cate = (const float*)d_in[0];
  const float* segx = (const float*)d_in[1];
  const float* segy = (const float*)d_in[2];
  char* ws = (char*)d_ws;
  float* out = (float*)d_out;

  hipMemsetAsync(ws, 0, ZERO_BYTES, stream);

  dim3 gFlat((NFLAT + 255) / 256);
  hipLaunchKernelGGL(kh1, gFlat, dim3(256), 0, stream, cate, ws);
  hipLaunchKernelGGL(kc1, dim3(1), dim3(1024), 0, stream, ws);
  hipLaunchKernelGGL(kg, gFlat, dim3(256), 0, stream, cate, ws);
  hipLaunchKernelGGL(kselw, dim3(1), dim3(1024), 0, stream, ws);
  hipLaunchKernelGGL(kmask, dim3(NPRE), dim3(256), 0, stream, segx, segy, ws);
  hipLaunchKernelGGL(ksp, dim3(1), dim3(512), 0, stream, ws);
  hipLaunchKernelGGL(kpiou, dim3(2048), dim3(64), 0, stream, ws);
  hipLaunchKernelGGL(knms, dim3(1), dim3(512), 0, stream, ws, out);
  hipLaunchKernelGGL(kout, dim3(MAXOUT * NRBLK), dim3(256), 0, stream, segx, segy, ws, out);
}

// Round 5
// 377.464 us; speedup vs baseline: 1.8451x; 1.4656x over previous
//
#include <hip/hip_runtime.h>
#include <stdint.h>

typedef unsigned int u32;
typedef unsigned long long u64;

#define NCELLS  3872
#define NCLS    80
#define NFLAT   309760
#define NPRE    500
#define NPAD    512
#define HH      200
#define WW      304
#define NPIX    60800
#define NWORDS  950      // 60800 / 64 exactly
#define MSTRIDE 960
#define MAXOUT  100
#define OH      427
#define OW      640
#define MH      800
#define MW      1216
#define MAXG    4096
#define MAXPAIRS 16384
#define OUT_LBL 27328000
#define OUT_SCR 27328100
#define ROWS_PER_BLK 2
#define NRBLK 214        // ceil(427/2)

#define S_THR 0.1f
#define M_THR 0.005f
#define U_THR 0.001f

// ---------------- workspace layout (bytes) ----------------
#define OFF_HIST1   0u        // 65536 u32 (value-bins: bin = (int)(v*65536))
#define OFF_HIST2   262144u   // 256 u32 (unused, kept zeroed)
#define OFF_META    263168u   // 16 u32: [0]cutbin [1]cntAbove [2]cutBin [3]gatherCnt [4]pairCnt
#define ZERO_BYTES  263232u
#define OFF_CAND    263424u   // 4096 u64
#define OFF_RAW     296192u   // 512 f32
#define OFF_LOC     298240u
#define OFF_LABEL   300288u
#define OFF_XIND    302336u
#define OFF_YIND    304384u
#define OFF_STRIDE  306432u
#define OFF_SMF     308480u
#define OFF_SCORE   310528u
#define OFF_LABELK  312576u
#define OFF_ORDER   314624u
#define OFF_SSCORE  316672u
#define OFF_TOPC    318720u   // 128 i32
#define OFF_PAIRI   319232u   // 16384 u32
#define OFF_PAIRIOU 384768u   // 16384 f32
#define OFF_W1YT0   450304u   // 800 i32
#define OFF_W1YA    453504u   // 800 f32
#define OFF_W1YB    456704u
#define OFF_W1XT0   459904u   // 1216 i32
#define OFF_W1XA    464768u
#define OFF_W1XB    469632u
#define OFF_W2YS    474496u   // 427 i32
#define OFF_W2YW    476224u   // 427*4 f32
#define OFF_W2XS    483072u   // 640 i32
#define OFF_W2XW    485632u   // 640*4 f32
#define OFF_MASKS   495872u   // 500*960 u64  (8-aligned)

#define P_U32(off) ((u32*)(ws + (off)))
#define P_I32(off) ((int*)(ws + (off)))
#define P_F32(off) ((float*)(ws + (off)))
#define P_U64(off) ((u64*)(ws + (off)))

__device__ __forceinline__ void levelMeta(int loc, int& td, int& sd, int& ng, float& st) {
  if (loc < 1600)      { td = 0;    sd = 0;   ng = 40; st = 4.f;  }
  else if (loc < 2896) { td = 1600; sd = 40;  ng = 36; st = 8.f;  }
  else if (loc < 3472) { td = 2896; sd = 76;  ng = 24; st = 16.f; }
  else if (loc < 3728) { td = 3472; sd = 100; ng = 16; st = 32.f; }
  else                 { td = 3728; sd = 116; ng = 12; st = 64.f; }
}

// value bin: exact & monotone for positive f32 (mult by 2^16 is exact scaling)
__device__ __forceinline__ u32 vbin(float v) {
  int b = (int)(v * 65536.0f);
  if (b > 65535) b = 65535;
  if (b < 0) b = 0;
  return (u32)b;
}

// -------- stage 1: top-500 selection (value-bin histogram, low contention) --------
__global__ void kh1(const float* __restrict__ cate, char* __restrict__ ws) {
  int i = blockIdx.x * 256 + threadIdx.x;
  if (i >= NFLAT) return;
  float v = cate[i];
  if (v > S_THR) atomicAdd(&P_U32(OFF_HIST1)[vbin(v)], 1u);
}

// find the value-bin containing the 500th value; gather threshold = that bin
__global__ __launch_bounds__(1024) void kc1(char* __restrict__ ws) {
  __shared__ u32 cs[1024];
  int t = threadIdx.x;
  const u32* h = P_U32(OFF_HIST1);
  u32 s = 0;
  for (int b = 0; b < 64; b++) s += h[t * 64 + b];
  cs[t] = s;
  __syncthreads();
  if (t == 0) {
    u32* meta = P_U32(OFF_META);
    u32 cum = 0; int cb = -1;
    for (int c = 1023; c >= 0; c--) {
      if (cum + cs[c] >= NPRE) { cb = c; break; }
      cum += cs[c];
    }
    u32 bin = 0;
    if (cb >= 0) {
      bin = (u32)(cb * 64);
      for (int b = cb * 64 + 63; b >= cb * 64; b--) {
        u32 hb = h[b];
        if (cum + hb >= NPRE) { bin = (u32)b; break; }
        cum += hb;
      }
    }
    meta[0] = bin; meta[1] = cum;
    meta[2] = bin;                 // cut value-bin (bucket ~ handful of values)
  }
}

__global__ void kg(const float* __restrict__ cate, char* __restrict__ ws) {
  u32 key = P_U32(OFF_META)[2];
  int i = blockIdx.x * 256 + threadIdx.x;
  if (i >= NFLAT) return;
  float v = cate[i];
  if (v > S_THR) {
    if (vbin(v) >= key) {
      u32 pos = atomicAdd(&P_U32(OFF_META)[3], 1u);
      if (pos < MAXG) P_U64(OFF_CAND)[pos] = (((u64)__float_as_uint(v)) << 32) | (u32)(~(u32)i);
    }
  }
}

// bitonic top-500 + candidate metadata + (fused) resize weight tables
__global__ __launch_bounds__(1024) void kselw(char* __restrict__ ws) {
  __shared__ u64 sk[MAXG];
  int tid = threadIdx.x;
  int G = (int)P_U32(OFF_META)[3]; if (G > MAXG) G = MAXG;
  const u64* cand = P_U64(OFF_CAND);
  for (int i = tid; i < MAXG; i += 1024) sk[i] = (i < G) ? cand[i] : 0ull;
  __syncthreads();
  for (int k = 2; k <= MAXG; k <<= 1) {
    for (int j = k >> 1; j > 0; j >>= 1) {
      for (int i = tid; i < MAXG; i += 1024) {
        int l = i ^ j;
        if (l > i) {
          u64 a = sk[i], b = sk[l];
          bool sw = ((i & k) == 0) ? (a < b) : (a > b);
          if (sw) { sk[i] = b; sk[l] = a; }
        }
      }
      __syncthreads();
    }
  }
  if (tid < NPAD) {
    float rawv = -1.f; int loc = 0, lab = -1, xi = 0, yi = 0; float st = 3.0e38f;
    if (tid < NPRE && tid < G) {
      u64 key = sk[tid];
      u32 b = (u32)(key >> 32);
      u32 idx = ~((u32)(key & 0xffffffffu));
      rawv = __uint_as_float(b);
      loc = (int)(idx / (u32)NCLS);
      lab = (int)(idx - (u32)loc * NCLS);
      int td, sd, ng; levelMeta(loc, td, sd, ng, st);
      int rel = loc - td;
      int row = rel / ng;
      yi = row + sd;
      xi = (rel - row * ng) + sd;
    }
    P_F32(OFF_RAW)[tid] = rawv;
    P_I32(OFF_LOC)[tid] = loc;
    P_I32(OFF_LABEL)[tid] = lab;
    P_I32(OFF_XIND)[tid] = xi;
    P_I32(OFF_YIND)[tid] = yi;
    P_F32(OFF_STRIDE)[tid] = st;
    P_F32(OFF_SCORE)[tid] = 0.f;
    P_I32(OFF_LABELK)[tid] = -1;
    P_F32(OFF_SMF)[tid] = 0.f;
  }
  // ---- fused: resize weight tables (mimic jax.image.resize f32 math) ----
  int t = tid;
  for (int r = t; r < MH; r += 1024) {
    float s1 = ((float)r + 0.5f) * 0.25f - 0.5f;
    int t0 = (int)floorf(s1);
    float f = s1 - (float)t0;
    float wa = 1.f - f, wb = f;
    bool ia = (t0 >= 0) && (t0 < HH);
    bool ib = ((t0 + 1) >= 0) && ((t0 + 1) < HH);
    float tw = (ia ? wa : 0.f) + (ib ? wb : 0.f);
    float na = ia ? (wa / tw) : 0.f;
    float nb = ib ? (wb / tw) : 0.f;
    int base; float A, B;
    if (t0 < 0) { base = 0; A = nb; B = 0.f; }
    else if (t0 >= HH - 1) { base = HH - 2; A = 0.f; B = na; }
    else { base = t0; A = na; B = nb; }
    P_I32(OFF_W1YT0)[r] = base;
    P_F32(OFF_W1YA)[r] = A;
    P_F32(OFF_W1YB)[r] = B;
  }
  for (int c = t; c < MW; c += 1024) {
    float s1 = ((float)c + 0.5f) * 0.25f - 0.5f;
    int t0 = (int)floorf(s1);
    float f = s1 - (float)t0;
    float wa = 1.f - f, wb = f;
    bool ia = (t0 >= 0) && (t0 < WW);
    bool ib = ((t0 + 1) >= 0) && ((t0 + 1) < WW);
    float tw = (ia ? wa : 0.f) + (ib ? wb : 0.f);
    float na = ia ? (wa / tw) : 0.f;
    float nb = ib ? (wb / tw) : 0.f;
    int base; float A, B;
    if (t0 < 0) { base = 0; A = nb; B = 0.f; }
    else if (t0 >= WW - 1) { base = WW - 2; A = 0.f; B = na; }
    else { base = t0; A = na; B = nb; }
    P_I32(OFF_W1XT0)[c] = base;
    P_F32(OFF_W1XA)[c] = A;
    P_F32(OFF_W1XB)[c] = B;
  }
  for (int o = t; o < OH; o += 1024) {
    const float inv = (float)(800.0 / 427.0);
    float s2 = ((float)o + 0.5f) * inv - 0.5f;
    int rA = (int)ceilf(s2 - inv);
    int rB = (int)floorf(s2 + inv);
    if (rA < 0) rA = 0;
    if (rB > MH - 1) rB = MH - 1;
    float tot = 0.f;
    for (int r = rA; r <= rB; r++) {
      float x = fabsf(s2 - (float)r) / inv;
      float w = 1.f - x; if (w < 0.f) w = 0.f;
      tot += w;
    }
    int base = rA; if (base > MH - 4) base = MH - 4;
    float o4[4] = {0.f, 0.f, 0.f, 0.f};
    for (int r = rA; r <= rB; r++) {
      float x = fabsf(s2 - (float)r) / inv;
      float w = 1.f - x; if (w < 0.f) w = 0.f;
      o4[r - base] += w / tot;
    }
    P_I32(OFF_W2YS)[o] = base;
    float* wp = P_F32(OFF_W2YW) + o * 4;
    wp[0] = o4[0]; wp[1] = o4[1]; wp[2] = o4[2]; wp[3] = o4[3];
  }
  for (int o = t; o < OW; o += 1024) {
    const float inv = (float)(1216.0 / 640.0);
    float s2 = ((float)o + 0.5f) * inv - 0.5f;
    int rA = (int)ceilf(s2 - inv);
    int rB = (int)floorf(s2 + inv);
    if (rA < 0) rA = 0;
    if (rB > MW - 1) rB = MW - 1;
    float tot = 0.f;
    for (int r = rA; r <= rB; r++) {
      float x = fabsf(s2 - (float)r) / inv;
      float w = 1.f - x; if (w < 0.f) w = 0.f;
      tot += w;
    }
    int base = rA; if (base > MW - 4) base = MW - 4;
    float o4[4] = {0.f, 0.f, 0.f, 0.f};
    for (int r = rA; r <= rB; r++) {
      float x = fabsf(s2 - (float)r) / inv;
      float w = 1.f - x; if (w < 0.f) w = 0.f;
      o4[r - base] += w / tot;
    }
    P_I32(OFF_W2XS)[o] = base;
    float* wp = P_F32(OFF_W2XW) + o * 4;
    wp[0] = o4[0]; wp[1] = o4[1]; wp[2] = o4[2]; wp[3] = o4[3];
  }
}

// -------- stage 2: per-candidate bit-packed mask + seg-score --------
__global__ __launch_bounds__(256) void kmask(const float* __restrict__ segx, const float* __restrict__ segy,
                                             char* __restrict__ ws) {
  int c = blockIdx.x;
  int tid = threadIdx.x;
  int lane = tid & 63, wv = tid >> 6;
  const float* X = segx + (size_t)P_I32(OFF_XIND)[c] * NPIX;
  const float* Y = segy + (size_t)P_I32(OFF_YIND)[c] * NPIX;
  u64* mrow = P_U64(OFF_MASKS) + (size_t)c * MSTRIDE;
  int cnt = 0;
  double ssum = 0.0;
  for (int w0 = wv; w0 < NWORDS; w0 += 4) {
    int p = (w0 << 6) + lane;
    float s = X[p] * Y[p];
    bool b = s > M_THR;
    u64 bal = __ballot(b ? 1 : 0);
    if (lane == 0) mrow[w0] = bal;
    if (b) { cnt++; ssum += (double)s; }
  }
  __shared__ int ci[256];
  __shared__ double cd[256];
  ci[tid] = cnt; cd[tid] = ssum;
  __syncthreads();
  for (int s2 = 128; s2 > 0; s2 >>= 1) {
    if (tid < s2) { ci[tid] += ci[tid + s2]; cd[tid] += cd[tid + s2]; }
    __syncthreads();
  }
  if (tid == 0) {
    float sm = (float)ci[0];
    float rawv = P_F32(OFF_RAW)[c];
    bool valid = rawv > S_THR;
    bool keep = valid && (sm > P_F32(OFF_STRIDE)[c]);
    float ssf = (float)cd[0];
    float segsc = ssf / fmaxf(sm, 1e-6f);
    P_F32(OFF_SCORE)[c] = keep ? (rawv * segsc) : 0.f;
    P_F32(OFF_SMF)[c] = keep ? sm : 0.f;
    P_I32(OFF_LABELK)[c] = keep ? P_I32(OFF_LABEL)[c] : -1;
  }
}

// -------- stage 3+4: stable descending sort of 500 scores + same-class pair list --------
__global__ __launch_bounds__(512) void ksp(char* __restrict__ ws) {
  __shared__ u64 sk[NPAD];
  __shared__ short slab[NPAD];
  __shared__ u32 scan[NPAD];
  int t = threadIdx.x;
  float sc = (t < NPRE) ? P_F32(OFF_SCORE)[t] : 0.f;
  sk[t] = (((u64)__float_as_uint(sc)) << 32) | (u32)(NPAD - 1 - t);
  __syncthreads();
  for (int k = 2; k <= NPAD; k <<= 1) {
    for (int j = k >> 1; j > 0; j >>= 1) {
      int l = t ^ j;
      if (l > t) {
        u64 a = sk[t], b = sk[l];
        bool sw = ((t & k) == 0) ? (a < b) : (a > b);
        if (sw) { sk[t] = b; sk[l] = a; }
      }
      __syncthreads();
    }
  }
  int ord = NPAD - 1 - (int)(sk[t] & 0xffffffffu);
  P_I32(OFF_ORDER)[t] = ord;
  P_F32(OFF_SSCORE)[t] = __uint_as_float((u32)(sk[t] >> 32));
  // pairs
  const int* labelK = P_I32(OFF_LABELK);
  int lab = (t < NPRE) ? labelK[ord] : -1;
  slab[t] = (short)lab;
  __syncthreads();
  u32 cnt = 0;
  if (lab >= 0) {
    short lj = (short)lab;
    for (int i = 0; i < t; i++) if (slab[i] == lj) cnt++;
  }
  scan[t] = cnt;
  __syncthreads();
  for (int off = 1; off < NPAD; off <<= 1) {
    u32 v = (t >= off) ? scan[t - off] : 0u;
    __syncthreads();
    scan[t] += v;
    __syncthreads();
  }
  if (t == NPAD - 1) {
    u32 tot = scan[t];
    P_U32(OFF_META)[4] = (tot > MAXPAIRS) ? MAXPAIRS : tot;
  }
  if (lab >= 0 && cnt) {
    u32 pos = scan[t] - cnt;
    short lj = (short)lab;
    u32* pairI = P_U32(OFF_PAIRI);
    for (int i = 0; i < t; i++) {
      if (slab[i] == lj) {
        if (pos < MAXPAIRS) pairI[pos] = (((u32)i) << 16) | (u32)t;
        pos++;
      }
    }
  }
}

__global__ __launch_bounds__(64) void kpiou(char* __restrict__ ws) {
  int P = (int)P_U32(OFF_META)[4]; if (P > MAXPAIRS) P = MAXPAIRS;
  const int* order = P_I32(OFF_ORDER);
  const float* smf = P_F32(OFF_SMF);
  const u64* masks = P_U64(OFF_MASKS);
  for (int p = blockIdx.x; p < P; p += gridDim.x) {
    u32 ij = P_U32(OFF_PAIRI)[p];
    int oi = order[ij >> 16];
    int oj = order[ij & 0xffffu];
    const u64* mi = masks + (size_t)oi * MSTRIDE;
    const u64* mj = masks + (size_t)oj * MSTRIDE;
    int inter = 0;
    for (int w = threadIdx.x; w < NWORDS; w += 64)
      inter += (int)__popcll(mi[w] & mj[w]);
    for (int off = 32; off > 0; off >>= 1)
      inter += __shfl_down(inter, off);
    if (threadIdx.x == 0) {
      float fi = (float)inter;
      float uni = (smf[oj] + smf[oi]) - fi;
      float iou = (uni > 0.f) ? (fi / fmaxf(uni, 1e-12f)) : 0.f;
      P_F32(OFF_PAIRIOU)[p] = iou;
    }
  }
}

// -------- stage 5: matrix-NMS decay + top-100 + labels/scores out --------
__global__ __launch_bounds__(512) void knms(char* __restrict__ ws, float* __restrict__ out) {
  __shared__ int compI[NPAD];
  __shared__ int coefI[NPAD];
  __shared__ u64 sk[NPAD];
  int t = threadIdx.x;
  int P = (int)P_U32(OFF_META)[4]; if (P > MAXPAIRS) P = MAXPAIRS;
  const u32* pairI = P_U32(OFF_PAIRI);
  const float* pairIou = P_F32(OFF_PAIRIOU);
  const float* sscore = P_F32(OFF_SSCORE);
  const int* order = P_I32(OFF_ORDER);
  const int* labelK = P_I32(OFF_LABELK);
  int* topc = P_I32(OFF_TOPC);
  compI[t] = 0;
  coefI[t] = __float_as_int(1.0f);
  __syncthreads();
  for (int p = t; p < P; p += 512) {
    int j = (int)(pairI[p] & 0xffffu);
    atomicMax(&compI[j], __float_as_int(pairIou[p]));
  }
  __syncthreads();
  for (int p = t; p < P; p += 512) {
    u32 ij = pairI[p];
    int i = (int)(ij >> 16), j = (int)(ij & 0xffffu);
    float x = pairIou[p];
    float c = __int_as_float(compI[i]);
    float x2 = x * x, c2 = c * c;
    float r = (float)exp(-2.0 * ((double)x2 - (double)c2));
    atomicMin(&coefI[j], __float_as_int(r));
  }
  __syncthreads();
  float ns = 0.f;
  if (t < NPRE) {
    ns = sscore[t] * __int_as_float(coefI[t]);
    ns = (ns > U_THR) ? ns : 0.f;
  }
  sk[t] = (((u64)__float_as_uint(ns)) << 32) | (u32)(NPAD - 1 - t);
  __syncthreads();
  for (int k = 2; k <= NPAD; k <<= 1) {
    for (int j = k >> 1; j > 0; j >>= 1) {
      int l = t ^ j;
      if (l > t) {
        u64 a = sk[t], b = sk[l];
        bool sw = ((t & k) == 0) ? (a < b) : (a > b);
        if (sw) { sk[t] = b; sk[l] = a; }
      }
      __syncthreads();
    }
  }
  if (t < MAXOUT) {
    u64 key = sk[t];
    int pos = NPAD - 1 - (int)(key & 0xffffffffu);
    int cand = order[pos];
    topc[t] = cand;
    out[OUT_LBL + t] = (float)labelK[cand];
    out[OUT_SCR + t] = __uint_as_float((u32)(key >> 32));
  }
}

// -------- stage 7: fused double-resize + binarize; one block = (mask, 2 out-rows) --------
__global__ __launch_bounds__(256) void kout(const float* __restrict__ segx, const float* __restrict__ segy,
                                            char* __restrict__ ws, float* __restrict__ out) {
  __shared__ float ss[4][WW];    // src-row products X*Y
  __shared__ float t1s[6][WW];   // y-interp mid rows (stage-1 vertical)
  __shared__ float yrs[2][MW];   // per-out-row y-contracted mid columns
  int bx = blockIdx.x;
  int kk = bx / NRBLK;
  int r2 = bx - kk * NRBLK;
  int oy0 = r2 * ROWS_PER_BLK;
  int nrow = (oy0 + 1 < OH) ? 2 : 1;
  int tid = threadIdx.x;
  int cand = P_I32(OFF_TOPC)[kk];
  const float* X = segx + (size_t)P_I32(OFF_XIND)[cand] * NPIX;
  const float* Y = segy + (size_t)P_I32(OFF_YIND)[cand] * NPIX;
  const int* w2ys = P_I32(OFF_W2YS);
  int rb = w2ys[oy0];
  const int* w1yT0 = P_I32(OFF_W1YT0);
  int smin = w1yT0[rb];
  for (int idx = tid; idx < 4 * WW; idx += 256) {
    int q = idx / WW;
    int u = idx - q * WW;
    int row = smin + q; if (row > HH - 1) row = HH - 1;
    ss[q][u] = X[row * WW + u] * Y[row * WW + u];
  }
  __syncthreads();
  const float* w1yA = P_F32(OFF_W1YA);
  const float* w1yB = P_F32(OFF_W1YB);
  for (int idx = tid; idx < 6 * WW; idx += 256) {
    int mr = idx / WW;
    int u = idx - mr * WW;
    int r = rb + mr; if (r > MH - 1) r = MH - 1;
    int i0 = w1yT0[r] - smin;          // in [0,2]
    t1s[mr][u] = fmaf(w1yB[r], ss[i0 + 1][u], w1yA[r] * ss[i0][u]);
  }
  __syncthreads();
  const int* w1xT0 = P_I32(OFF_W1XT0);
  const float* w1xA = P_F32(OFF_W1XA);
  const float* w1xB = P_F32(OFF_W1XB);
  const float* w2yw = P_F32(OFF_W2YW);
  for (int idx = tid; idx < nrow * MW; idx += 256) {
    int rr = idx / MW;
    int cc = idx - rr * MW;
    int oy = oy0 + rr;
    int off = w2ys[oy] - rb;           // in [0,2]
    const float* wy = w2yw + oy * 4;
    int u0 = w1xT0[cc];
    float xa = w1xA[cc], xb = w1xB[cc];
    float up0 = fmaf(xb, t1s[off][u0 + 1],     xa * t1s[off][u0]);
    float up1 = fmaf(xb, t1s[off + 1][u0 + 1], xa * t1s[off + 1][u0]);
    float up2 = fmaf(xb, t1s[off + 2][u0 + 1], xa * t1s[off + 2][u0]);
    float up3 = fmaf(xb, t1s[off + 3][u0 + 1], xa * t1s[off + 3][u0]);
    float v = wy[0] * up0;
    v = fmaf(wy[1], up1, v);
    v = fmaf(wy[2], up2, v);
    v = fmaf(wy[3], up3, v);
    yrs[rr][cc] = v;
  }
  __syncthreads();
  const int* w2xS = P_I32(OFF_W2XS);
  const float* w2xW = P_F32(OFF_W2XW);
  for (int idx = tid; idx < nrow * OW; idx += 256) {
    int rr = idx / OW;
    int ox = idx - rr * OW;
    int oy = oy0 + rr;
    int cb = w2xS[ox];
    const float* wx = w2xW + ox * 4;
    float acc = wx[0] * yrs[rr][cb];
    acc = fmaf(wx[1], yrs[rr][cb + 1], acc);
    acc = fmaf(wx[2], yrs[rr][cb + 2], acc);
    acc = fmaf(wx[3], yrs[rr][cb + 3], acc);
    out[((size_t)kk * OH + oy) * OW + ox] = (acc > M_THR) ? 1.0f : 0.0f;
  }
}

extern "C" void kernel_launch(void* const* d_in, const int* in_sizes, int n_in,
                              void* d_out, int out_size, void* d_ws, size_t ws_size,
                              hipStream_t stream) {
  (void)in_sizes; (void)n_in; (void)out_size; (void)ws_size;
  const float* cate = (const float*)d_in[0];
  const float* segx = (const float*)d_in[1];
  const float* segy = (const float*)d_in[2];
  char* ws = (char*)d_ws;
  float* out = (float*)d_out;

  hipMemsetAsync(ws, 0, ZERO_BYTES, stream);

  dim3 gFlat((NFLAT + 255) / 256);
  hipLaunchKernelGGL(kh1, gFlat, dim3(256), 0, stream, cate, ws);
  hipLaunchKernelGGL(kc1, dim3(1), dim3(1024), 0, stream, ws);
  hipLaunchKernelGGL(kg, gFlat, dim3(256), 0, stream, cate, ws);
  hipLaunchKernelGGL(kselw, dim3(1), dim3(1024), 0, stream, ws);
  hipLaunchKernelGGL(kmask, dim3(NPRE), dim3(256), 0, stream, segx, segy, ws);
  hipLaunchKernelGGL(ksp, dim3(1), dim3(512), 0, stream, ws);
  hipLaunchKernelGGL(kpiou, dim3(2048), dim3(64), 0, stream, ws);
  hipLaunchKernelGGL(knms, dim3(1), dim3(512), 0, stream, ws, out);
  hipLaunchKernelGGL(kout, dim3(MAXOUT * NRBLK), dim3(256), 0, stream, segx, segy, ws, out);
}

// Round 6
// 355.099 us; speedup vs baseline: 1.9613x; 1.0630x over previous
//
#include <hip/hip_runtime.h>
#include <stdint.h>

typedef unsigned int u32;
typedef unsigned long long u64;

#define NCELLS  3872
#define NCLS    80
#define NFLAT   309760
#define NPRE    500
#define NPAD    512
#define HH      200
#define WW      304
#define NPIX    60800
#define NWORDS  950      // 60800 / 64 exactly
#define MSTRIDE 960
#define MAXOUT  100
#define OH      427
#define OW      640
#define MH      800
#define MW      1216
#define MAXG    4096
#define MAXPAIRS 16384
#define OUT_LBL 27328000
#define OUT_SCR 27328100
#define ROWS_PER_BLK 2
#define NRBLK 214        // ceil(427/2); 100*214 = 21400 = 8*2675

#define S_THR 0.1f
#define M_THR 0.005f
#define U_THR 0.001f

// ---------------- workspace layout (bytes) ----------------
#define OFF_HIST1   0u        // 65536 u32 (value-bins: bin = (int)(v*65536))
#define OFF_META    263168u   // 16 u32: [0]cutbin [1]cntAbove [2]cutBin [3]gatherCnt [4]pairCnt
#define ZERO_BYTES  263232u
#define OFF_CAND    263424u   // 4096 u64
#define OFF_RAW     296192u   // 512 f32
#define OFF_LOC     298240u
#define OFF_LABEL   300288u
#define OFF_XIND    302336u
#define OFF_YIND    304384u
#define OFF_STRIDE  306432u
#define OFF_SMF     308480u
#define OFF_SCORE   310528u
#define OFF_LABELK  312576u
#define OFF_ORDER   314624u
#define OFF_SSCORE  316672u
#define OFF_TOPC    318720u   // 128 i32
#define OFF_PAIRI   319232u   // 16384 u32
#define OFF_PAIRIOU 384768u   // 16384 f32
#define OFF_W1YT0   450304u   // 800 i32
#define OFF_W1YA    453504u   // 800 f32
#define OFF_W1YB    456704u
#define OFF_W1XT0   459904u   // 1216 i32
#define OFF_W1XA    464768u
#define OFF_W1XB    469632u
#define OFF_W2YS    474496u   // 427 i32
#define OFF_W2YW    476224u   // 427*4 f32 (16B aligned)
#define OFF_W2XS    483072u   // 640 i32
#define OFF_W2XW    485632u   // 640*4 f32 (16B aligned)
#define OFF_MASKS   495872u   // 500*960 u64
#define OFF_PARTD   4335872u  // 500*950 f64 partial seg-score sums
#define WS_NEED     8135872u

#define P_U32(off) ((u32*)(ws + (off)))
#define P_I32(off) ((int*)(ws + (off)))
#define P_F32(off) ((float*)(ws + (off)))
#define P_U64(off) ((u64*)(ws + (off)))

__device__ __forceinline__ void levelMeta(int loc, int& td, int& sd, int& ng, float& st) {
  if (loc < 1600)      { td = 0;    sd = 0;   ng = 40; st = 4.f;  }
  else if (loc < 2896) { td = 1600; sd = 40;  ng = 36; st = 8.f;  }
  else if (loc < 3472) { td = 2896; sd = 76;  ng = 24; st = 16.f; }
  else if (loc < 3728) { td = 3472; sd = 100; ng = 16; st = 32.f; }
  else                 { td = 3728; sd = 116; ng = 12; st = 64.f; }
}

// value bin: exact & monotone for positive f32
__device__ __forceinline__ u32 vbin(float v) {
  int b = (int)(v * 65536.0f);
  if (b > 65535) b = 65535;
  if (b < 0) b = 0;
  return (u32)b;
}

// -------- stage 1: top-500 selection (value-bin histogram, low contention) --------
__global__ void kh1(const float* __restrict__ cate, char* __restrict__ ws) {
  int i = blockIdx.x * 256 + threadIdx.x;
  if (i >= NFLAT) return;
  float v = cate[i];
  if (v > S_THR) atomicAdd(&P_U32(OFF_HIST1)[vbin(v)], 1u);
}

// parallel suffix-scan to find the value-bin containing the 500th value
__global__ __launch_bounds__(1024) void kc1(char* __restrict__ ws) {
  __shared__ u32 cs[1024];
  __shared__ u32 sfx[1024];
  __shared__ int cbS;
  __shared__ u32 aboveS;
  int t = threadIdx.x;
  const u32* h = P_U32(OFF_HIST1);
  u32 s = 0;
  for (int b = 0; b < 64; b++) s += h[t * 64 + b];
  cs[t] = s; sfx[t] = s;
  if (t == 0) cbS = -1;
  __syncthreads();
  for (int off = 1; off < 1024; off <<= 1) {
    u32 v = (t + off < 1024) ? sfx[t + off] : 0u;
    __syncthreads();
    sfx[t] += v;
    __syncthreads();
  }
  u32 nxt = (t < 1023) ? sfx[t + 1] : 0u;
  if (sfx[t] >= NPRE && nxt < NPRE) { cbS = t; aboveS = nxt; }
  __syncthreads();
  u32* meta = P_U32(OFF_META);
  if (cbS < 0) {                       // fewer than 500 above threshold
    if (t == 0) { meta[0] = 0u; meta[1] = sfx[0]; meta[2] = 0u; }
    return;
  }
  int cb = cbS;
  if (t < 64) cs[t] = h[cb * 64 + t];
  __syncthreads();
  if (t == 0) {
    u32 cum = aboveS;
    u32 bin = (u32)(cb * 64);
    for (int b = 63; b >= 0; b--) {
      u32 hb = cs[b];
      if (cum + hb >= NPRE) { bin = (u32)(cb * 64 + b); break; }
      cum += hb;
    }
    meta[0] = bin; meta[1] = cum; meta[2] = bin;
  }
}

__global__ void kg(const float* __restrict__ cate, char* __restrict__ ws) {
  u32 key = P_U32(OFF_META)[2];
  int i = blockIdx.x * 256 + threadIdx.x;
  if (i >= NFLAT) return;
  float v = cate[i];
  if (v > S_THR) {
    if (vbin(v) >= key) {
      u32 pos = atomicAdd(&P_U32(OFF_META)[3], 1u);
      if (pos < MAXG) P_U64(OFF_CAND)[pos] = (((u64)__float_as_uint(v)) << 32) | (u32)(~(u32)i);
    }
  }
}

// bitonic top-500 (dynamic network size) + candidate metadata + resize weight tables
__global__ __launch_bounds__(1024) void kselw(char* __restrict__ ws) {
  __shared__ u64 sk[MAXG];
  int tid = threadIdx.x;
  int G = (int)P_U32(OFF_META)[3]; if (G > MAXG) G = MAXG;
  int n = NPAD;                       // next pow2 >= max(G, 512)
  while (n < G) n <<= 1;
  const u64* cand = P_U64(OFF_CAND);
  for (int i = tid; i < n; i += 1024) sk[i] = (i < G) ? cand[i] : 0ull;
  __syncthreads();
  for (int k = 2; k <= n; k <<= 1) {
    for (int j = k >> 1; j > 0; j >>= 1) {
      for (int i = tid; i < n; i += 1024) {
        int l = i ^ j;
        if (l > i) {
          u64 a = sk[i], b = sk[l];
          bool sw = ((i & k) == 0) ? (a < b) : (a > b);
          if (sw) { sk[i] = b; sk[l] = a; }
        }
      }
      __syncthreads();
    }
  }
  if (tid < NPAD) {
    float rawv = -1.f; int loc = 0, lab = -1, xi = 0, yi = 0; float st = 3.0e38f;
    if (tid < NPRE && tid < G) {
      u64 key = sk[tid];
      u32 b = (u32)(key >> 32);
      u32 idx = ~((u32)(key & 0xffffffffu));
      rawv = __uint_as_float(b);
      loc = (int)(idx / (u32)NCLS);
      lab = (int)(idx - (u32)loc * NCLS);
      int td, sd, ng; levelMeta(loc, td, sd, ng, st);
      int rel = loc - td;
      int row = rel / ng;
      yi = row + sd;
      xi = (rel - row * ng) + sd;
    }
    P_F32(OFF_RAW)[tid] = rawv;
    P_I32(OFF_LABEL)[tid] = lab;
    P_I32(OFF_XIND)[tid] = xi;
    P_I32(OFF_YIND)[tid] = yi;
    P_F32(OFF_STRIDE)[tid] = st;
    P_F32(OFF_SCORE)[tid] = 0.f;
    P_I32(OFF_LABELK)[tid] = -1;
    P_F32(OFF_SMF)[tid] = 0.f;
  }
  // ---- fused: resize weight tables (mimic jax.image.resize f32 math) ----
  int t = tid;
  for (int r = t; r < MH; r += 1024) {
    float s1 = ((float)r + 0.5f) * 0.25f - 0.5f;
    int t0 = (int)floorf(s1);
    float f = s1 - (float)t0;
    float wa = 1.f - f, wb = f;
    bool ia = (t0 >= 0) && (t0 < HH);
    bool ib = ((t0 + 1) >= 0) && ((t0 + 1) < HH);
    float tw = (ia ? wa : 0.f) + (ib ? wb : 0.f);
    float na = ia ? (wa / tw) : 0.f;
    float nb = ib ? (wb / tw) : 0.f;
    int base; float A, B;
    if (t0 < 0) { base = 0; A = nb; B = 0.f; }
    else if (t0 >= HH - 1) { base = HH - 2; A = 0.f; B = na; }
    else { base = t0; A = na; B = nb; }
    P_I32(OFF_W1YT0)[r] = base;
    P_F32(OFF_W1YA)[r] = A;
    P_F32(OFF_W1YB)[r] = B;
  }
  for (int c = t; c < MW; c += 1024) {
    float s1 = ((float)c + 0.5f) * 0.25f - 0.5f;
    int t0 = (int)floorf(s1);
    float f = s1 - (float)t0;
    float wa = 1.f - f, wb = f;
    bool ia = (t0 >= 0) && (t0 < WW);
    bool ib = ((t0 + 1) >= 0) && ((t0 + 1) < WW);
    float tw = (ia ? wa : 0.f) + (ib ? wb : 0.f);
    float na = ia ? (wa / tw) : 0.f;
    float nb = ib ? (wb / tw) : 0.f;
    int base; float A, B;
    if (t0 < 0) { base = 0; A = nb; B = 0.f; }
    else if (t0 >= WW - 1) { base = WW - 2; A = 0.f; B = na; }
    else { base = t0; A = na; B = nb; }
    P_I32(OFF_W1XT0)[c] = base;
    P_F32(OFF_W1XA)[c] = A;
    P_F32(OFF_W1XB)[c] = B;
  }
  for (int o = t; o < OH; o += 1024) {
    const float inv = (float)(800.0 / 427.0);
    float s2 = ((float)o + 0.5f) * inv - 0.5f;
    int rA = (int)ceilf(s2 - inv);
    int rB = (int)floorf(s2 + inv);
    if (rA < 0) rA = 0;
    if (rB > MH - 1) rB = MH - 1;
    float tot = 0.f;
    for (int r = rA; r <= rB; r++) {
      float x = fabsf(s2 - (float)r) / inv;
      float w = 1.f - x; if (w < 0.f) w = 0.f;
      tot += w;
    }
    int base = rA; if (base > MH - 4) base = MH - 4;
    float o4[4] = {0.f, 0.f, 0.f, 0.f};
    for (int r = rA; r <= rB; r++) {
      float x = fabsf(s2 - (float)r) / inv;
      float w = 1.f - x; if (w < 0.f) w = 0.f;
      o4[r - base] += w / tot;
    }
    P_I32(OFF_W2YS)[o] = base;
    float* wp = P_F32(OFF_W2YW) + o * 4;
    wp[0] = o4[0]; wp[1] = o4[1]; wp[2] = o4[2]; wp[3] = o4[3];
  }
  for (int o = t; o < OW; o += 1024) {
    const float inv = (float)(1216.0 / 640.0);
    float s2 = ((float)o + 0.5f) * inv - 0.5f;
    int rA = (int)ceilf(s2 - inv);
    int rB = (int)floorf(s2 + inv);
    if (rA < 0) rA = 0;
    if (rB > MW - 1) rB = MW - 1;
    float tot = 0.f;
    for (int r = rA; r <= rB; r++) {
      float x = fabsf(s2 - (float)r) / inv;
      float w = 1.f - x; if (w < 0.f) w = 0.f;
      tot += w;
    }
    int base = rA; if (base > MW - 4) base = MW - 4;
    float o4[4] = {0.f, 0.f, 0.f, 0.f};
    for (int r = rA; r <= rB; r++) {
      float x = fabsf(s2 - (float)r) / inv;
      float w = 1.f - x; if (w < 0.f) w = 0.f;
      o4[r - base] += w / tot;
    }
    P_I32(OFF_W2XS)[o] = base;
    float* wp = P_F32(OFF_W2XW) + o * 4;
    wp[0] = o4[0]; wp[1] = o4[1]; wp[2] = o4[2]; wp[3] = o4[3];
  }
}

// -------- stage 2 (new): word-major mask build; LDS-shared seg rows --------
// one block = one 64-px word; all 256 seg-row slices staged in 64 KB LDS;
// each wave computes 125 candidates' ballot word + f64 partial sum.
__global__ __launch_bounds__(256) void kmaskA(const float* __restrict__ segx, const float* __restrict__ segy,
                                              char* __restrict__ ws) {
  __shared__ float lx[128][64];
  __shared__ float ly[128][64];
  int w0 = blockIdx.x;
  int base = w0 << 6;
  int tid = threadIdx.x;
  for (int idx = tid; idx < 128 * 16; idx += 256) {
    int r = idx >> 4, q = idx & 15;
    float4 vx = *(const float4*)(segx + (size_t)r * NPIX + base + q * 4);
    float4 vy = *(const float4*)(segy + (size_t)r * NPIX + base + q * 4);
    *(float4*)(&lx[r][q * 4]) = vx;
    *(float4*)(&ly[r][q * 4]) = vy;
  }
  __syncthreads();
  int lane = tid & 63, wv = tid >> 6;
  const int* xind = P_I32(OFF_XIND);
  const int* yind = P_I32(OFF_YIND);
  u64* masks = P_U64(OFF_MASKS);
  double* partD = (double*)(ws + OFF_PARTD);
  for (int c = wv; c < NPRE; c += 4) {
    int xi = xind[c], yi = yind[c];
    float s = lx[xi][lane] * ly[yi][lane];
    bool b = s > M_THR;
    u64 bal = __ballot(b ? 1 : 0);
    double d = b ? (double)s : 0.0;
    #pragma unroll
    for (int off = 32; off > 0; off >>= 1) d += __shfl_xor(d, off);
    if (lane == 0) {
      masks[(size_t)c * MSTRIDE + w0] = bal;
      partD[(size_t)c * NWORDS + w0] = d;
    }
  }
}

// deterministic per-candidate reduction + keep logic
__global__ __launch_bounds__(256) void kmaskB(char* __restrict__ ws) {
  __shared__ double cd[256];
  __shared__ int ci[256];
  int c = blockIdx.x;
  int tid = threadIdx.x;
  const double* partD = (const double*)(ws + OFF_PARTD) + (size_t)c * NWORDS;
  const u64* mrow = P_U64(OFF_MASKS) + (size_t)c * MSTRIDE;
  double ds = 0.0; int cnt = 0;
  for (int w = tid; w < NWORDS; w += 256) { ds += partD[w]; cnt += (int)__popcll(mrow[w]); }
  cd[tid] = ds; ci[tid] = cnt;
  __syncthreads();
  for (int s2 = 128; s2 > 0; s2 >>= 1) {
    if (tid < s2) { ci[tid] += ci[tid + s2]; cd[tid] += cd[tid + s2]; }
    __syncthreads();
  }
  if (tid == 0) {
    float sm = (float)ci[0];
    float rawv = P_F32(OFF_RAW)[c];
    bool valid = rawv > S_THR;
    bool keep = valid && (sm > P_F32(OFF_STRIDE)[c]);
    float ssf = (float)cd[0];
    float segsc = ssf / fmaxf(sm, 1e-6f);
    P_F32(OFF_SCORE)[c] = keep ? (rawv * segsc) : 0.f;
    P_F32(OFF_SMF)[c] = keep ? sm : 0.f;
    P_I32(OFF_LABELK)[c] = keep ? P_I32(OFF_LABEL)[c] : -1;
  }
}

// -------- stage 2 (fallback, candidate-major) if workspace is small --------
__global__ __launch_bounds__(256) void kmask(const float* __restrict__ segx, const float* __restrict__ segy,
                                             char* __restrict__ ws) {
  int c = blockIdx.x;
  int tid = threadIdx.x;
  int lane = tid & 63, wv = tid >> 6;
  const float* X = segx + (size_t)P_I32(OFF_XIND)[c] * NPIX;
  const float* Y = segy + (size_t)P_I32(OFF_YIND)[c] * NPIX;
  u64* mrow = P_U64(OFF_MASKS) + (size_t)c * MSTRIDE;
  int cnt = 0;
  double ssum = 0.0;
  for (int w0 = wv; w0 < NWORDS; w0 += 4) {
    int p = (w0 << 6) + lane;
    float s = X[p] * Y[p];
    bool b = s > M_THR;
    u64 bal = __ballot(b ? 1 : 0);
    if (lane == 0) mrow[w0] = bal;
    if (b) { cnt++; ssum += (double)s; }
  }
  __shared__ int ci[256];
  __shared__ double cd[256];
  ci[tid] = cnt; cd[tid] = ssum;
  __syncthreads();
  for (int s2 = 128; s2 > 0; s2 >>= 1) {
    if (tid < s2) { ci[tid] += ci[tid + s2]; cd[tid] += cd[tid + s2]; }
    __syncthreads();
  }
  if (tid == 0) {
    float sm = (float)ci[0];
    float rawv = P_F32(OFF_RAW)[c];
    bool valid = rawv > S_THR;
    bool keep = valid && (sm > P_F32(OFF_STRIDE)[c]);
    float ssf = (float)cd[0];
    float segsc = ssf / fmaxf(sm, 1e-6f);
    P_F32(OFF_SCORE)[c] = keep ? (rawv * segsc) : 0.f;
    P_F32(OFF_SMF)[c] = keep ? sm : 0.f;
    P_I32(OFF_LABELK)[c] = keep ? P_I32(OFF_LABEL)[c] : -1;
  }
}

// -------- stage 3+4: stable descending sort of 500 scores + same-class pair list --------
__global__ __launch_bounds__(512) void ksp(char* __restrict__ ws) {
  __shared__ u64 sk[NPAD];
  __shared__ short slab[NPAD];
  __shared__ u32 scan[NPAD];
  int t = threadIdx.x;
  float sc = (t < NPRE) ? P_F32(OFF_SCORE)[t] : 0.f;
  sk[t] = (((u64)__float_as_uint(sc)) << 32) | (u32)(NPAD - 1 - t);
  __syncthreads();
  for (int k = 2; k <= NPAD; k <<= 1) {
    for (int j = k >> 1; j > 0; j >>= 1) {
      int l = t ^ j;
      if (l > t) {
        u64 a = sk[t], b = sk[l];
        bool sw = ((t & k) == 0) ? (a < b) : (a > b);
        if (sw) { sk[t] = b; sk[l] = a; }
      }
      __syncthreads();
    }
  }
  int ord = NPAD - 1 - (int)(sk[t] & 0xffffffffu);
  P_I32(OFF_ORDER)[t] = ord;
  P_F32(OFF_SSCORE)[t] = __uint_as_float((u32)(sk[t] >> 32));
  const int* labelK = P_I32(OFF_LABELK);
  int lab = (t < NPRE) ? labelK[ord] : -1;
  slab[t] = (short)lab;
  __syncthreads();
  u32 cnt = 0;
  if (lab >= 0) {
    short lj = (short)lab;
    for (int i = 0; i < t; i++) if (slab[i] == lj) cnt++;
  }
  scan[t] = cnt;
  __syncthreads();
  for (int off = 1; off < NPAD; off <<= 1) {
    u32 v = (t >= off) ? scan[t - off] : 0u;
    __syncthreads();
    scan[t] += v;
    __syncthreads();
  }
  if (t == NPAD - 1) {
    u32 tot = scan[t];
    P_U32(OFF_META)[4] = (tot > MAXPAIRS) ? MAXPAIRS : tot;
  }
  if (lab >= 0 && cnt) {
    u32 pos = scan[t] - cnt;
    short lj = (short)lab;
    u32* pairI = P_U32(OFF_PAIRI);
    for (int i = 0; i < t; i++) {
      if (slab[i] == lj) {
        if (pos < MAXPAIRS) pairI[pos] = (((u32)i) << 16) | (u32)t;
        pos++;
      }
    }
  }
}

__global__ __launch_bounds__(64) void kpiou(char* __restrict__ ws) {
  int P = (int)P_U32(OFF_META)[4]; if (P > MAXPAIRS) P = MAXPAIRS;
  const int* order = P_I32(OFF_ORDER);
  const float* smf = P_F32(OFF_SMF);
  const u64* masks = P_U64(OFF_MASKS);
  for (int p = blockIdx.x; p < P; p += gridDim.x) {
    u32 ij = P_U32(OFF_PAIRI)[p];
    int oi = order[ij >> 16];
    int oj = order[ij & 0xffffu];
    const u64* mi = masks + (size_t)oi * MSTRIDE;
    const u64* mj = masks + (size_t)oj * MSTRIDE;
    int inter = 0;
    for (int w = threadIdx.x; w < NWORDS; w += 64)
      inter += (int)__popcll(mi[w] & mj[w]);
    for (int off = 32; off > 0; off >>= 1)
      inter += __shfl_down(inter, off);
    if (threadIdx.x == 0) {
      float fi = (float)inter;
      float uni = (smf[oj] + smf[oi]) - fi;
      float iou = (uni > 0.f) ? (fi / fmaxf(uni, 1e-12f)) : 0.f;
      P_F32(OFF_PAIRIOU)[p] = iou;
    }
  }
}

// -------- stage 5: matrix-NMS decay + top-100 + labels/scores out --------
__global__ __launch_bounds__(512) void knms(char* __restrict__ ws, float* __restrict__ out) {
  __shared__ int compI[NPAD];
  __shared__ int coefI[NPAD];
  __shared__ u64 sk[NPAD];
  int t = threadIdx.x;
  int P = (int)P_U32(OFF_META)[4]; if (P > MAXPAIRS) P = MAXPAIRS;
  const u32* pairI = P_U32(OFF_PAIRI);
  const float* pairIou = P_F32(OFF_PAIRIOU);
  const float* sscore = P_F32(OFF_SSCORE);
  const int* order = P_I32(OFF_ORDER);
  const int* labelK = P_I32(OFF_LABELK);
  int* topc = P_I32(OFF_TOPC);
  compI[t] = 0;
  coefI[t] = __float_as_int(1.0f);
  __syncthreads();
  for (int p = t; p < P; p += 512) {
    int j = (int)(pairI[p] & 0xffffu);
    atomicMax(&compI[j], __float_as_int(pairIou[p]));
  }
  __syncthreads();
  for (int p = t; p < P; p += 512) {
    u32 ij = pairI[p];
    int i = (int)(ij >> 16), j = (int)(ij & 0xffffu);
    float x = pairIou[p];
    float c = __int_as_float(compI[i]);
    float x2 = x * x, c2 = c * c;
    float r = (float)exp(-2.0 * ((double)x2 - (double)c2));
    atomicMin(&coefI[j], __float_as_int(r));
  }
  __syncthreads();
  float ns = 0.f;
  if (t < NPRE) {
    ns = sscore[t] * __int_as_float(coefI[t]);
    ns = (ns > U_THR) ? ns : 0.f;
  }
  sk[t] = (((u64)__float_as_uint(ns)) << 32) | (u32)(NPAD - 1 - t);
  __syncthreads();
  for (int k = 2; k <= NPAD; k <<= 1) {
    for (int j = k >> 1; j > 0; j >>= 1) {
      int l = t ^ j;
      if (l > t) {
        u64 a = sk[t], b = sk[l];
        bool sw = ((t & k) == 0) ? (a < b) : (a > b);
        if (sw) { sk[t] = b; sk[l] = a; }
      }
      __syncthreads();
    }
  }
  if (t < MAXOUT) {
    u64 key = sk[t];
    int pos = NPAD - 1 - (int)(key & 0xffffffffu);
    int cand = order[pos];
    topc[t] = cand;
    out[OUT_LBL + t] = (float)labelK[cand];
    out[OUT_SCR + t] = __uint_as_float((u32)(key >> 32));
  }
}

// -------- stage 7: fused double-resize + binarize; XCD-bijective block swizzle --------
__global__ __launch_bounds__(256) void kout(const float* __restrict__ segx, const float* __restrict__ segy,
                                            char* __restrict__ ws, float* __restrict__ out) {
  __shared__ float ss[4][WW];
  __shared__ float t1s[6][WW];
  __shared__ float yrs[2][MW];
  // bijective XCD swizzle: 21400 = 8 * 2675; same-kk blocks cluster per XCD
  int flat = blockIdx.x;
  int w = (flat & 7) * 2675 + (flat >> 3);
  int kk = w / NRBLK;
  int r2 = w - kk * NRBLK;
  int oy0 = r2 * ROWS_PER_BLK;
  int nrow = (oy0 + 1 < OH) ? 2 : 1;
  int tid = threadIdx.x;
  int cand = P_I32(OFF_TOPC)[kk];
  const float* X = segx + (size_t)P_I32(OFF_XIND)[cand] * NPIX;
  const float* Y = segy + (size_t)P_I32(OFF_YIND)[cand] * NPIX;
  const int* w2ys = P_I32(OFF_W2YS);
  int rb = w2ys[oy0];
  const int* w1yT0 = P_I32(OFF_W1YT0);
  int smin = w1yT0[rb];
  // stage 0: src-row products
  for (int q = 0; q < 4; q++) {
    int row = smin + q; if (row > HH - 1) row = HH - 1;
    const float* Xr = X + row * WW;
    const float* Yr = Y + row * WW;
    for (int u = tid; u < WW; u += 256) ss[q][u] = Xr[u] * Yr[u];
  }
  __syncthreads();
  // stage 1: y-interp mid rows
  const float* w1yA = P_F32(OFF_W1YA);
  const float* w1yB = P_F32(OFF_W1YB);
  for (int mr = 0; mr < 6; mr++) {
    int r = rb + mr; if (r > MH - 1) r = MH - 1;
    int i0 = w1yT0[r] - smin;
    float A = w1yA[r], B = w1yB[r];
    const float* s0 = &ss[i0][0];
    const float* s1 = &ss[i0 + 1][0];
    for (int u = tid; u < WW; u += 256) t1s[mr][u] = fmaf(B, s1[u], A * s0[u]);
  }
  __syncthreads();
  // stage 2+3a: x-upsample on the fly + y-contraction, once per mid column
  const int* w1xT0 = P_I32(OFF_W1XT0);
  const float* w1xA = P_F32(OFF_W1XA);
  const float* w1xB = P_F32(OFF_W1XB);
  for (int rr = 0; rr < nrow; rr++) {
    int oy = oy0 + rr;
    int off = w2ys[oy] - rb;
    float4 wy = *(const float4*)(P_F32(OFF_W2YW) + oy * 4);
    const float* r0 = &t1s[off][0];
    const float* r1 = &t1s[off + 1][0];
    const float* r2p = &t1s[off + 2][0];
    const float* r3 = &t1s[off + 3][0];
    for (int cc = tid; cc < MW; cc += 256) {
      int u0 = w1xT0[cc];
      float xa = w1xA[cc], xb = w1xB[cc];
      float up0 = fmaf(xb, r0[u0 + 1], xa * r0[u0]);
      float up1 = fmaf(xb, r1[u0 + 1], xa * r1[u0]);
      float up2 = fmaf(xb, r2p[u0 + 1], xa * r2p[u0]);
      float up3 = fmaf(xb, r3[u0 + 1], xa * r3[u0]);
      float v = wy.x * up0;
      v = fmaf(wy.y, up1, v);
      v = fmaf(wy.z, up2, v);
      v = fmaf(wy.w, up3, v);
      yrs[rr][cc] = v;
    }
  }
  __syncthreads();
  // stage 3b: x-contraction + binarize + store
  const int* w2xS = P_I32(OFF_W2XS);
  for (int rr = 0; rr < nrow; rr++) {
    int oy = oy0 + rr;
    size_t ob = ((size_t)kk * OH + oy) * OW;
    const float* yr = &yrs[rr][0];
    for (int ox = tid; ox < OW; ox += 256) {
      int cb = w2xS[ox];
      float4 wx = *(const float4*)(P_F32(OFF_W2XW) + ox * 4);
      float acc = wx.x * yr[cb];
      acc = fmaf(wx.y, yr[cb + 1], acc);
      acc = fmaf(wx.z, yr[cb + 2], acc);
      acc = fmaf(wx.w, yr[cb + 3], acc);
      out[ob + ox] = (acc > M_THR) ? 1.0f : 0.0f;
    }
  }
}

extern "C" void kernel_launch(void* const* d_in, const int* in_sizes, int n_in,
                              void* d_out, int out_size, void* d_ws, size_t ws_size,
                              hipStream_t stream) {
  (void)in_sizes; (void)n_in; (void)out_size;
  const float* cate = (const float*)d_in[0];
  const float* segx = (const float*)d_in[1];
  const float* segy = (const float*)d_in[2];
  char* ws = (char*)d_ws;
  float* out = (float*)d_out;
  const bool bigws = (ws_size >= (size_t)WS_NEED);   // constant per-session -> capture-safe

  hipMemsetAsync(ws, 0, ZERO_BYTES, stream);

  dim3 gFlat((NFLAT + 255) / 256);
  hipLaunchKernelGGL(kh1, gFlat, dim3(256), 0, stream, cate, ws);
  hipLaunchKernelGGL(kc1, dim3(1), dim3(1024), 0, stream, ws);
  hipLaunchKernelGGL(kg, gFlat, dim3(256), 0, stream, cate, ws);
  hipLaunchKernelGGL(kselw, dim3(1), dim3(1024), 0, stream, ws);
  if (bigws) {
    hipLaunchKernelGGL(kmaskA, dim3(NWORDS), dim3(256), 0, stream, segx, segy, ws);
    hipLaunchKernelGGL(kmaskB, dim3(NPRE), dim3(256), 0, stream, ws);
  } else {
    hipLaunchKernelGGL(kmask, dim3(NPRE), dim3(256), 0, stream, segx, segy, ws);
  }
  hipLaunchKernelGGL(ksp, dim3(1), dim3(512), 0, stream, ws);
  hipLaunchKernelGGL(kpiou, dim3(2048), dim3(64), 0, stream, ws);
  hipLaunchKernelGGL(knms, dim3(1), dim3(512), 0, stream, ws, out);
  hipLaunchKernelGGL(kout, dim3(MAXOUT * NRBLK), dim3(256), 0, stream, segx, segy, ws, out);
}